// Round 1
// baseline (95.225 us; speedup 1.0000x reference)
//
#include <hip/hip_runtime.h>
#include <hip/hip_bf16.h>
#include <cstddef>

// Problem constants
// B=16, NC=128, NP=256, C=128, HID=256, MAXN=386, N_PROT=16384
// out layout (floats):
//  [0)       compound_coords_out : 6144
//  [6144)    compound_batch      : 2048
//  [8192)    pocket_coords_out   : 12288
//  [20480)   pocket_batch        : 4096
//  [24576)   y_pred              : 524288
//  [548864)  y_pred_by_coords    : 524288
//  [1073152) dis_map (copy)      : 524288
//  [1597440) keepNode_less_5     : 1

// ---------------------------------------------------------------------------
// K1: pocket_emb[4096][128] = protein[keep_idx] @ W_prot(1280x128) + b_prot
// 8 rows per block, 256 threads (c = tid&127, row-half = tid>>7 -> 4 accs)
__global__ __launch_bounds__(256) void k_pocket(const float* __restrict__ prot,
                                                const int* __restrict__ keep,
                                                const float* __restrict__ Wp,
                                                const float* __restrict__ bp,
                                                float* __restrict__ emb) {
    __shared__ float Al[8][128];
    __shared__ int ridx[8];
    const int tid = threadIdx.x;
    const int c = tid & 127;
    const int rh = tid >> 7;      // 0/1
    const int row0 = blockIdx.x * 8;
    if (tid < 8) ridx[tid] = keep[row0 + tid];
    float acc0 = 0.f, acc1 = 0.f, acc2 = 0.f, acc3 = 0.f;
    for (int kk = 0; kk < 1280; kk += 128) {
        __syncthreads();
#pragma unroll
        for (int i = 0; i < 4; ++i) {
            int li = tid + i * 256;          // 0..1023
            int r = li >> 7, k = li & 127;
            Al[r][k] = prot[(size_t)ridx[r] * 1280 + kk + k];
        }
        __syncthreads();
        const int rb = rh * 4;
#pragma unroll 4
        for (int k4 = 0; k4 < 128; k4 += 4) {
            float4 a0 = *reinterpret_cast<const float4*>(&Al[rb + 0][k4]);
            float4 a1 = *reinterpret_cast<const float4*>(&Al[rb + 1][k4]);
            float4 a2 = *reinterpret_cast<const float4*>(&Al[rb + 2][k4]);
            float4 a3 = *reinterpret_cast<const float4*>(&Al[rb + 3][k4]);
            float w0 = Wp[(kk + k4 + 0) * 128 + c];
            float w1 = Wp[(kk + k4 + 1) * 128 + c];
            float w2 = Wp[(kk + k4 + 2) * 128 + c];
            float w3 = Wp[(kk + k4 + 3) * 128 + c];
            acc0 += a0.x * w0 + a0.y * w1 + a0.z * w2 + a0.w * w3;
            acc1 += a1.x * w0 + a1.y * w1 + a1.z * w2 + a1.w * w3;
            acc2 += a2.x * w0 + a2.y * w1 + a2.z * w2 + a2.w * w3;
            acc3 += a3.x * w0 + a3.y * w1 + a3.z * w2 + a3.w * w3;
        }
    }
    const float bb = bp[c];
    const int rb = rh * 4;
    emb[(size_t)(row0 + rb + 0) * 128 + c] = acc0 + bb;
    emb[(size_t)(row0 + rb + 1) * 128 + c] = acc1 + bb;
    emb[(size_t)(row0 + rb + 2) * 128 + c] = acc2 + bb;
    emb[(size_t)(row0 + rb + 3) * 128 + c] = acc3 + bb;
}

// ---------------------------------------------------------------------------
// K2: compound_emb[2048][128] = compound_feats(2048x56) @ W_comp(56x128) + b_comp
__global__ __launch_bounds__(256) void k_comp(const float* __restrict__ cf,
                                              const float* __restrict__ Wc,
                                              const float* __restrict__ bc,
                                              float* __restrict__ emb) {
    const int o = blockIdx.x * 256 + threadIdx.x;   // < 262144
    const int row = o >> 7, c = o & 127;
    float acc = bc[c];
    for (int k = 0; k < 56; ++k) acc += cf[row * 56 + k] * Wc[(k << 7) + c];
    emb[o] = acc;
}

// ---------------------------------------------------------------------------
// K3: [P1;C1][6144][256] = emb[6144][128] @ W1(128x256) (+ b1 for pocket rows)
// 8 rows per block, 256 threads = 256 cols, 8 accs per thread
__global__ __launch_bounds__(256) void k_proj(const float* __restrict__ embAll,
                                              const float* __restrict__ W1,
                                              const float* __restrict__ b1,
                                              float* __restrict__ P) {
    __shared__ float Al[8][128];
    const int tid = threadIdx.x;       // output col h
    const int row0 = blockIdx.x * 8;
    {
        const int r = tid >> 5, k = (tid & 31) * 4;
        *reinterpret_cast<float4*>(&Al[r][k]) =
            *reinterpret_cast<const float4*>(embAll + (size_t)(row0 + r) * 128 + k);
    }
    __syncthreads();
    float acc[8];
#pragma unroll
    for (int r = 0; r < 8; ++r) acc[r] = 0.f;
#pragma unroll 4
    for (int k4 = 0; k4 < 128; k4 += 4) {
        float w0 = W1[(k4 + 0) * 256 + tid];
        float w1 = W1[(k4 + 1) * 256 + tid];
        float w2 = W1[(k4 + 2) * 256 + tid];
        float w3 = W1[(k4 + 3) * 256 + tid];
#pragma unroll
        for (int r = 0; r < 8; ++r) {
            float4 a = *reinterpret_cast<const float4*>(&Al[r][k4]);
            acc[r] += a.x * w0 + a.y * w1 + a.z * w2 + a.w * w3;
        }
    }
    const float bb = (row0 < 4096) ? b1[tid] : 0.f;   // 4096 % 8 == 0, no straddle
#pragma unroll
    for (int r = 0; r < 8; ++r) P[(size_t)(row0 + r) * 256 + tid] = acc[r] + bb;
}

// ---------------------------------------------------------------------------
// K5: pair stage. Per block: 32 p x 32 c tile for one batch b.
// logits[p,c] = sum_h relu(P1[p,h] + C1[c,h]) * W2[h];  y = 10*sigmoid(logits+b2)
// Also dmap output. LDS XOR-swizzled (colblk ^ ((row>>1)&7)) for conflict-free b128.
__device__ __forceinline__ float relu_dot4(const float4 p, const float4 c, const float4 w) {
    return fmaxf(p.x + c.x, 0.f) * w.x + fmaxf(p.y + c.y, 0.f) * w.y +
           fmaxf(p.z + c.z, 0.f) * w.z + fmaxf(p.w + c.w, 0.f) * w.w;
}

__global__ __launch_bounds__(256) void k_pair(const float* __restrict__ P1,
                                              const float* __restrict__ C1,
                                              const float* __restrict__ W2,
                                              const float* __restrict__ b2,
                                              const float* __restrict__ coords,
                                              float* __restrict__ ypred,
                                              float* __restrict__ ycrd) {
    __shared__ float Pl[32 * 128];
    __shared__ float Cl[32 * 128];
    __shared__ float pcs[32][3], ccs[32][3];
    const int tid = threadIdx.x;
    const int b = blockIdx.z, p0 = blockIdx.y * 32, c0 = blockIdx.x * 32;
    if (tid < 32) {
        const float* s = coords + (size_t)(b * 386 + 130 + p0 + tid) * 3;
        pcs[tid][0] = s[0] / 5.0f; pcs[tid][1] = s[1] / 5.0f; pcs[tid][2] = s[2] / 5.0f;
    } else if (tid < 64) {
        const int t = tid & 31;
        const float* s = coords + (size_t)(b * 386 + 1 + c0 + t) * 3;
        ccs[t][0] = s[0] / 5.0f; ccs[t][1] = s[1] / 5.0f; ccs[t][2] = s[2] / 5.0f;
    }
    const int tpi = tid >> 4, tci = tid & 15;
    const int pr0 = 2 * tpi, pr1 = 2 * tpi + 1;
    const int cr0 = 2 * tci, cr1 = 2 * tci + 1;
    float a00 = 0.f, a01 = 0.f, a10 = 0.f, a11 = 0.f;

    for (int h0 = 0; h0 < 256; h0 += 128) {
        __syncthreads();
#pragma unroll
        for (int i = 0; i < 4; ++i) {
            int li = tid + i * 256;          // 0..1023
            int r = li >> 5, hb = li & 31;
            int sw = hb ^ ((r >> 1) & 7);
            float4 pv = *reinterpret_cast<const float4*>(
                P1 + (size_t)(b * 256 + p0 + r) * 256 + h0 + hb * 4);
            float4 cv = *reinterpret_cast<const float4*>(
                C1 + (size_t)(b * 128 + c0 + r) * 256 + h0 + hb * 4);
            *reinterpret_cast<float4*>(&Pl[r * 128 + sw * 4]) = pv;
            *reinterpret_cast<float4*>(&Cl[r * 128 + sw * 4]) = cv;
        }
        __syncthreads();
#pragma unroll 4
        for (int hb = 0; hb < 32; ++hb) {
            float4 wv = *reinterpret_cast<const float4*>(W2 + h0 + hb * 4);
            float4 pa = *reinterpret_cast<const float4*>(&Pl[pr0 * 128 + (hb ^ (tpi & 7)) * 4]);
            float4 pb = *reinterpret_cast<const float4*>(&Pl[pr1 * 128 + (hb ^ (tpi & 7)) * 4]);
            float4 ca = *reinterpret_cast<const float4*>(&Cl[cr0 * 128 + (hb ^ (tci & 7)) * 4]);
            float4 cb = *reinterpret_cast<const float4*>(&Cl[cr1 * 128 + (hb ^ (tci & 7)) * 4]);
            a00 += relu_dot4(pa, ca, wv);
            a01 += relu_dot4(pa, cb, wv);
            a10 += relu_dot4(pb, ca, wv);
            a11 += relu_dot4(pb, cb, wv);
        }
    }

    const float bb = b2[0];
    float accs[2][2] = {{a00, a01}, {a10, a11}};
#pragma unroll
    for (int i = 0; i < 2; ++i) {
#pragma unroll
        for (int j = 0; j < 2; ++j) {
            const int pr = 2 * tpi + i, cr = 2 * tci + j;
            const float logit = accs[i][j] + bb;
            const float y = 10.0f / (1.0f + expf(-logit));
            const float dx = pcs[pr][0] - ccs[cr][0];
            const float dy = pcs[pr][1] - ccs[cr][1];
            const float dz = pcs[pr][2] - ccs[cr][2];
            const float d = sqrtf(dx * dx + dy * dy + dz * dz + 1e-12f);
            const float yc = fminf(fmaxf(d * 5.0f, 0.0f), 10.0f);
            const size_t o = (size_t)(b * 256 + p0 + pr) * 128 + (c0 + cr);
            ypred[o] = y;
            ycrd[o] = yc;
        }
    }
}

// ---------------------------------------------------------------------------
// K6: misc outputs: dis_map copy, coords*5 passthroughs, batch indices, keepNode
__global__ __launch_bounds__(256) void k_misc(const float* __restrict__ dism,
                                              const float* __restrict__ coords,
                                              float* __restrict__ out) {
    const int i = blockIdx.x * 256 + threadIdx.x;   // 0..524287
    out[1073152 + i] = dism[i];                     // dis_map passthrough
    if (i < 6144) {                                 // compound_coords_out
        const int row = i / 3, d = i - row * 3;
        const int b = row >> 7, c = row & 127;
        const float x = coords[(size_t)(b * 386 + 1 + c) * 3 + d];
        out[i] = (x / 5.0f) * 5.0f;
    }
    if (i < 2048) out[6144 + i] = (float)(i >> 7);  // compound_batch
    if (i < 12288) {                                // pocket_coords_out
        const int row = i / 3, d = i - row * 3;
        const int b = row >> 8, p = row & 255;
        const float x = coords[(size_t)(b * 386 + 130 + p) * 3 + d];
        out[8192 + i] = (x / 5.0f) * 5.0f;
    }
    if (i < 4096) out[20480 + i] = (float)(i >> 8); // pocket_batch
    if (i == 0) out[1597440] = 0.0f;                // keepNode_less_5
}

// ---------------------------------------------------------------------------
extern "C" void kernel_launch(void* const* d_in, const int* in_sizes, int n_in,
                              void* d_out, int out_size, void* d_ws, size_t ws_size,
                              hipStream_t stream) {
    const float* prot   = (const float*)d_in[0];
    const float* comp   = (const float*)d_in[1];
    const float* coords = (const float*)d_in[2];
    const float* dism   = (const float*)d_in[3];
    const int*   keep   = (const int*)d_in[4];
    // d_in[5], d_in[6] (glb_c, glb_p) are all-ones and algebraically unused
    const float* Wp = (const float*)d_in[7];
    const float* bp = (const float*)d_in[8];
    const float* Wc = (const float*)d_in[9];
    const float* bc = (const float*)d_in[10];
    const float* W1 = (const float*)d_in[11];
    const float* b1 = (const float*)d_in[12];
    const float* W2 = (const float*)d_in[13];
    const float* b2 = (const float*)d_in[14];
    float* out = (float*)d_out;
    float* ws = (float*)d_ws;

    float* pocketEmb = ws;              // 4096*128 = 524288 floats
    float* compEmb   = ws + 524288;     // 2048*128 = 262144 (contiguous after pocket)
    float* P1        = ws + 786432;     // 4096*256 = 1048576 (b1 folded in)
    float* C1        = ws + 1835008;    // 2048*256 = 524288 (contiguous after P1)
    // total ws use: 2359296 floats = 9.4 MB

    k_pocket<<<512, 256, 0, stream>>>(prot, keep, Wp, bp, pocketEmb);
    k_comp<<<1024, 256, 0, stream>>>(comp, Wc, bc, compEmb);
    k_proj<<<768, 256, 0, stream>>>(ws /* [pocketEmb; compEmb] */, W1, b1, P1);
    k_pair<<<dim3(4, 8, 16), 256, 0, stream>>>(P1, C1, W2, b2, coords,
                                               out + 24576, out + 548864);
    k_misc<<<2048, 256, 0, stream>>>(dism, coords, out);
}

// Round 2
// 59.514 us; speedup vs baseline: 1.6000x; 1.6000x over previous
//
#include <hip/hip_runtime.h>
#include <hip/hip_bf16.h>
#include <cstddef>

// Problem constants
// B=16, NC=128, NP=256, C=128, HID=256, MAXN=386, N_PROT=16384
// out layout (floats):
//  [0)       compound_coords_out : 6144
//  [6144)    compound_batch      : 2048
//  [8192)    pocket_coords_out   : 12288
//  [20480)   pocket_batch        : 4096
//  [24576)   y_pred              : 524288
//  [548864)  y_pred_by_coords    : 524288
//  [1073152) dis_map (copy)      : 524288
//  [1597440) keepNode_less_5     : 1

typedef __attribute__((ext_vector_type(8))) short short8v;   // 8 bf16 (4 VGPR)
typedef __attribute__((ext_vector_type(4))) float f32x4;     // MFMA acc

__device__ __forceinline__ unsigned short f2bf(float x) {    // RNE f32->bf16
    unsigned int u = __float_as_uint(x);
    unsigned int r = (u + 0x7fffu + ((u >> 16) & 1u)) >> 16;
    return (unsigned short)r;
}

// ---------------------------------------------------------------------------
// K0: W_prot(1280x128 f32) -> Bt(128x1280 bf16)  (transpose + convert)
__global__ __launch_bounds__(256) void k_wt(const float* __restrict__ Wp,
                                            unsigned short* __restrict__ Bt) {
    __shared__ float T[64][65];
    const int tid = threadIdx.x;
    const int kk = blockIdx.x * 64, cc = blockIdx.y * 64;
    const int c = tid & 63, rq = tid >> 6;
#pragma unroll
    for (int i = 0; i < 16; ++i) {
        const int r = rq * 16 + i;
        T[r][c] = Wp[(size_t)(kk + r) * 128 + cc + c];
    }
    __syncthreads();
    const int cl = tid >> 2, klc = (tid & 3) * 16;
    unsigned int w[8];
#pragma unroll
    for (int j = 0; j < 8; ++j) {
        const unsigned int lo = f2bf(T[klc + 2 * j][cl]);
        const unsigned int hi = f2bf(T[klc + 2 * j + 1][cl]);
        w[j] = lo | (hi << 16);
    }
    unsigned int* dst = (unsigned int*)(Bt + (size_t)(cc + cl) * 1280 + kk + klc);
    *reinterpret_cast<uint4*>(dst) = make_uint4(w[0], w[1], w[2], w[3]);
    *reinterpret_cast<uint4*>(dst + 4) = make_uint4(w[4], w[5], w[6], w[7]);
}

// ---------------------------------------------------------------------------
// K1: pocket partial GEMM via MFMA.
// grid = (4096/64, NSPLIT). Block: 256 thr = 4 waves, tile 64(M) x 128(N),
// K-chunk = 1280/NSPLIT per block (iters of BK=64).
// Output: pp[split][4096][128] fp32 partials (bias added in split 0 only).
__global__ __launch_bounds__(256) void k_pocket_mfma(const float* __restrict__ prot,
                                                     const int* __restrict__ keep,
                                                     const unsigned short* __restrict__ Bt,
                                                     const float* __restrict__ bp,
                                                     float* __restrict__ pp,
                                                     int kchunk) {
    __shared__ __align__(16) char As[64 * 64 * 2];    // 8 KB  bf16 [row][k] swizzled
    __shared__ __align__(16) char Bs[128 * 64 * 2];   // 16 KB bf16 [col][k] swizzled
    __shared__ int keepL[64];
    const int tid = threadIdx.x;
    const int l = tid & 63, wid = tid >> 6;
    const int wm = wid & 1, wn = wid >> 1;            // wave tile: 32 rows x 64 cols
    const int m0 = blockIdx.x * 64;
    const int koff0 = blockIdx.y * kchunk;
    const int iters = kchunk >> 6;

    if (tid < 64) keepL[tid] = keep[m0 + tid];
    __syncthreads();

    f32x4 acc[2][4];
#pragma unroll
    for (int m = 0; m < 2; ++m)
#pragma unroll
        for (int n = 0; n < 4; ++n) acc[m][n] = (f32x4){0.f, 0.f, 0.f, 0.f};

    const int l15 = l & 15, lg = l >> 4;

    for (int it = 0; it < iters; ++it) {
        const int koff = koff0 + it * 64;
        // ---- stage A: 64 rows x 64 k fp32 -> bf16, 4 units/thread
#pragma unroll
        for (int u = 0; u < 4; ++u) {
            const int unit = tid + 256 * u;           // 0..1023
            const int r = unit >> 4, kc = unit & 15;  // kc: float4 chunk
            const float4 v = *reinterpret_cast<const float4*>(
                prot + (size_t)keepL[r] * 1280 + koff + kc * 4);
            const unsigned int lo = f2bf(v.x) | ((unsigned int)f2bf(v.y) << 16);
            const unsigned int hi = f2bf(v.z) | ((unsigned int)f2bf(v.w) << 16);
            const int wb = (r * 128 + kc * 8) ^ ((r & 7) << 4);
            *reinterpret_cast<uint2*>(As + wb) = make_uint2(lo, hi);
        }
        // ---- stage B: 128 cols x 64 k bf16 from Bt, 4 units/thread
#pragma unroll
        for (int u = 0; u < 4; ++u) {
            const int unit = tid + 256 * u;           // 0..1023
            const int ccol = unit >> 3, k8 = unit & 7;
            const uint4 v = *reinterpret_cast<const uint4*>(
                Bt + (size_t)ccol * 1280 + koff + k8 * 8);
            const int wb = (ccol * 128 + k8 * 16) ^ ((ccol & 7) << 4);
            *reinterpret_cast<uint4*>(Bs + wb) = v;
        }
        __syncthreads();
        // ---- compute: 2 k-steps of 32, 2x4 fragments
#pragma unroll
        for (int ks = 0; ks < 2; ++ks) {
            const int kbyte = ks * 64 + lg * 16;
            short8v a[2], b[4];
#pragma unroll
            for (int m = 0; m < 2; ++m) {
                const int row = wm * 32 + m * 16 + l15;
                a[m] = *reinterpret_cast<const short8v*>(
                    As + ((row * 128 + kbyte) ^ ((row & 7) << 4)));
            }
#pragma unroll
            for (int n = 0; n < 4; ++n) {
                const int col = wn * 64 + n * 16 + l15;
                b[n] = *reinterpret_cast<const short8v*>(
                    Bs + ((col * 128 + kbyte) ^ ((col & 7) << 4)));
            }
#pragma unroll
            for (int m = 0; m < 2; ++m)
#pragma unroll
                for (int n = 0; n < 4; ++n)
                    acc[m][n] = __builtin_amdgcn_mfma_f32_16x16x32_bf16(
                        a[m], b[n], acc[m][n], 0, 0, 0);
        }
        __syncthreads();
    }

    // ---- epilogue: C/D layout col = l&15, row = (l>>4)*4 + i  [m89-verified]
    float* dst = pp + (size_t)blockIdx.y * 524288;
    const bool addBias = (blockIdx.y == 0);
#pragma unroll
    for (int m = 0; m < 2; ++m) {
#pragma unroll
        for (int n = 0; n < 4; ++n) {
            const int col = wn * 64 + n * 16 + l15;
            const float bb = addBias ? bp[col] : 0.f;
#pragma unroll
            for (int i = 0; i < 4; ++i) {
                const int row = m0 + wm * 32 + m * 16 + lg * 4 + i;
                dst[(size_t)row * 128 + col] = acc[m][n][i] + bb;
            }
        }
    }
}

// ---------------------------------------------------------------------------
// K2: compound_emb[2048][128] = compound_feats(2048x56) @ W_comp(56x128) + b_comp
__global__ __launch_bounds__(256) void k_comp(const float* __restrict__ cf,
                                              const float* __restrict__ Wc,
                                              const float* __restrict__ bc,
                                              float* __restrict__ emb) {
    const int o = blockIdx.x * 256 + threadIdx.x;   // < 262144
    const int row = o >> 7, c = o & 127;
    float acc = bc[c];
    for (int k = 0; k < 56; ++k) acc += cf[row * 56 + k] * Wc[(k << 7) + c];
    emb[o] = acc;
}

// ---------------------------------------------------------------------------
// K3: [P1;C1][6144][256] = emb[6144][128] @ W1(128x256) (+ b1 for pocket rows)
// Pocket rows come from NS fp32 partials (summed on load); compound from compEmb.
template <int NS>
__global__ __launch_bounds__(256) void k_proj(const float* __restrict__ pp,
                                              const float* __restrict__ compEmb,
                                              const float* __restrict__ W1,
                                              const float* __restrict__ b1,
                                              float* __restrict__ P) {
    __shared__ float Al[8][128];
    const int tid = threadIdx.x;       // output col h
    const int row0 = blockIdx.x * 8;
    {
        const int r = tid >> 5, k = (tid & 31) * 4;
        float4 v;
        if (row0 < 4096) {
            const size_t idx = (size_t)(row0 + r) * 128 + k;
            v = *reinterpret_cast<const float4*>(pp + idx);
#pragma unroll
            for (int s = 1; s < NS; ++s) {
                const float4 w = *reinterpret_cast<const float4*>(pp + (size_t)s * 524288 + idx);
                v.x += w.x; v.y += w.y; v.z += w.z; v.w += w.w;
            }
        } else {
            v = *reinterpret_cast<const float4*>(compEmb + (size_t)(row0 - 4096 + r) * 128 + k);
        }
        *reinterpret_cast<float4*>(&Al[r][k]) = v;
    }
    __syncthreads();
    float acc[8];
#pragma unroll
    for (int r = 0; r < 8; ++r) acc[r] = 0.f;
#pragma unroll 4
    for (int k4 = 0; k4 < 128; k4 += 4) {
        float w0 = W1[(k4 + 0) * 256 + tid];
        float w1 = W1[(k4 + 1) * 256 + tid];
        float w2 = W1[(k4 + 2) * 256 + tid];
        float w3 = W1[(k4 + 3) * 256 + tid];
#pragma unroll
        for (int r = 0; r < 8; ++r) {
            float4 a = *reinterpret_cast<const float4*>(&Al[r][k4]);
            acc[r] += a.x * w0 + a.y * w1 + a.z * w2 + a.w * w3;
        }
    }
    const float bb = (row0 < 4096) ? b1[tid] : 0.f;   // 4096 % 8 == 0, no straddle
#pragma unroll
    for (int r = 0; r < 8; ++r) P[(size_t)(row0 + r) * 256 + tid] = acc[r] + bb;
}

// ---------------------------------------------------------------------------
// K5: pair stage. Per block: 32 p x 32 c tile for one batch b.
// logits[p,c] = sum_h relu(P1[p,h] + C1[c,h]) * W2[h];  y = 10*sigmoid(logits+b2)
__device__ __forceinline__ float relu_dot4(const float4 p, const float4 c, const float4 w) {
    return fmaxf(p.x + c.x, 0.f) * w.x + fmaxf(p.y + c.y, 0.f) * w.y +
           fmaxf(p.z + c.z, 0.f) * w.z + fmaxf(p.w + c.w, 0.f) * w.w;
}

__global__ __launch_bounds__(256) void k_pair(const float* __restrict__ P1,
                                              const float* __restrict__ C1,
                                              const float* __restrict__ W2,
                                              const float* __restrict__ b2,
                                              const float* __restrict__ coords,
                                              float* __restrict__ ypred,
                                              float* __restrict__ ycrd) {
    __shared__ float Pl[32 * 128];
    __shared__ float Cl[32 * 128];
    __shared__ float pcs[32][3], ccs[32][3];
    const int tid = threadIdx.x;
    const int b = blockIdx.z, p0 = blockIdx.y * 32, c0 = blockIdx.x * 32;
    if (tid < 32) {
        const float* s = coords + (size_t)(b * 386 + 130 + p0 + tid) * 3;
        pcs[tid][0] = s[0] / 5.0f; pcs[tid][1] = s[1] / 5.0f; pcs[tid][2] = s[2] / 5.0f;
    } else if (tid < 64) {
        const int t = tid & 31;
        const float* s = coords + (size_t)(b * 386 + 1 + c0 + t) * 3;
        ccs[t][0] = s[0] / 5.0f; ccs[t][1] = s[1] / 5.0f; ccs[t][2] = s[2] / 5.0f;
    }
    const int tpi = tid >> 4, tci = tid & 15;
    const int pr0 = 2 * tpi, pr1 = 2 * tpi + 1;
    const int cr0 = 2 * tci, cr1 = 2 * tci + 1;
    float a00 = 0.f, a01 = 0.f, a10 = 0.f, a11 = 0.f;

    for (int h0 = 0; h0 < 256; h0 += 128) {
        __syncthreads();
#pragma unroll
        for (int i = 0; i < 4; ++i) {
            int li = tid + i * 256;          // 0..1023
            int r = li >> 5, hb = li & 31;
            int sw = hb ^ ((r >> 1) & 7);
            float4 pv = *reinterpret_cast<const float4*>(
                P1 + (size_t)(b * 256 + p0 + r) * 256 + h0 + hb * 4);
            float4 cv = *reinterpret_cast<const float4*>(
                C1 + (size_t)(b * 128 + c0 + r) * 256 + h0 + hb * 4);
            *reinterpret_cast<float4*>(&Pl[r * 128 + sw * 4]) = pv;
            *reinterpret_cast<float4*>(&Cl[r * 128 + sw * 4]) = cv;
        }
        __syncthreads();
#pragma unroll 4
        for (int hb = 0; hb < 32; ++hb) {
            float4 wv = *reinterpret_cast<const float4*>(W2 + h0 + hb * 4);
            float4 pa = *reinterpret_cast<const float4*>(&Pl[pr0 * 128 + (hb ^ (tpi & 7)) * 4]);
            float4 pb = *reinterpret_cast<const float4*>(&Pl[pr1 * 128 + (hb ^ (tpi & 7)) * 4]);
            float4 ca = *reinterpret_cast<const float4*>(&Cl[cr0 * 128 + (hb ^ (tci & 7)) * 4]);
            float4 cb = *reinterpret_cast<const float4*>(&Cl[cr1 * 128 + (hb ^ (tci & 7)) * 4]);
            a00 += relu_dot4(pa, ca, wv);
            a01 += relu_dot4(pa, cb, wv);
            a10 += relu_dot4(pb, ca, wv);
            a11 += relu_dot4(pb, cb, wv);
        }
    }

    const float bb = b2[0];
    float accs[2][2] = {{a00, a01}, {a10, a11}};
#pragma unroll
    for (int i = 0; i < 2; ++i) {
#pragma unroll
        for (int j = 0; j < 2; ++j) {
            const int pr = 2 * tpi + i, cr = 2 * tci + j;
            const float logit = accs[i][j] + bb;
            const float y = 10.0f / (1.0f + expf(-logit));
            const float dx = pcs[pr][0] - ccs[cr][0];
            const float dy = pcs[pr][1] - ccs[cr][1];
            const float dz = pcs[pr][2] - ccs[cr][2];
            const float d = sqrtf(dx * dx + dy * dy + dz * dz + 1e-12f);
            const float yc = fminf(fmaxf(d * 5.0f, 0.0f), 10.0f);
            const size_t o = (size_t)(b * 256 + p0 + pr) * 128 + (c0 + cr);
            ypred[o] = y;
            ycrd[o] = yc;
        }
    }
}

// ---------------------------------------------------------------------------
// K6: misc outputs: dis_map copy, coords*5 passthroughs, batch indices, keepNode
__global__ __launch_bounds__(256) void k_misc(const float* __restrict__ dism,
                                              const float* __restrict__ coords,
                                              float* __restrict__ out) {
    const int i = blockIdx.x * 256 + threadIdx.x;   // 0..524287
    out[1073152 + i] = dism[i];                     // dis_map passthrough
    if (i < 6144) {                                 // compound_coords_out
        const int row = i / 3, d = i - row * 3;
        const int b = row >> 7, c = row & 127;
        const float x = coords[(size_t)(b * 386 + 1 + c) * 3 + d];
        out[i] = (x / 5.0f) * 5.0f;
    }
    if (i < 2048) out[6144 + i] = (float)(i >> 7);  // compound_batch
    if (i < 12288) {                                // pocket_coords_out
        const int row = i / 3, d = i - row * 3;
        const int b = row >> 8, p = row & 255;
        const float x = coords[(size_t)(b * 386 + 130 + p) * 3 + d];
        out[8192 + i] = (x / 5.0f) * 5.0f;
    }
    if (i < 4096) out[20480 + i] = (float)(i >> 8); // pocket_batch
    if (i == 0) out[1597440] = 0.0f;                // keepNode_less_5
}

// ---------------------------------------------------------------------------
extern "C" void kernel_launch(void* const* d_in, const int* in_sizes, int n_in,
                              void* d_out, int out_size, void* d_ws, size_t ws_size,
                              hipStream_t stream) {
    const float* prot   = (const float*)d_in[0];
    const float* comp   = (const float*)d_in[1];
    const float* coords = (const float*)d_in[2];
    const float* dism   = (const float*)d_in[3];
    const int*   keep   = (const int*)d_in[4];
    // d_in[5], d_in[6] (glb_c, glb_p) are all-ones and algebraically unused
    const float* Wp = (const float*)d_in[7];
    const float* bp = (const float*)d_in[8];
    const float* Wc = (const float*)d_in[9];
    const float* bc = (const float*)d_in[10];
    const float* W1 = (const float*)d_in[11];
    const float* b1 = (const float*)d_in[12];
    const float* W2 = (const float*)d_in[13];
    const float* b2 = (const float*)d_in[14];
    float* out = (float*)d_out;
    float* ws = (float*)d_ws;

    // ws layout (floats):
    //  pp       : NS * 524288 (pocket fp32 partials)
    //  compEmb  : 262144
    //  P1       : 1048576  (also aliases Bt bf16 [128*1280] early — dead by k_proj)
    //  C1       : 524288
    const size_t PP = 524288;
    const size_t tail = 262144 + 1048576 + 524288;
    int NS = 1;
    if (ws_size >= (4 * PP + tail) * sizeof(float)) NS = 4;
    else if (ws_size >= (2 * PP + tail) * sizeof(float)) NS = 2;
    float* pp      = ws;
    float* compEmb = ws + (size_t)NS * PP;
    float* P1      = compEmb + 262144;
    float* C1      = P1 + 1048576;
    unsigned short* Bt = (unsigned short*)P1;   // bf16 W^T, consumed before P1 written

    k_wt<<<dim3(20, 2), 256, 0, stream>>>(Wp, Bt);
    k_pocket_mfma<<<dim3(64, NS), 256, 0, stream>>>(prot, keep, Bt, bp, pp, 1280 / NS);
    k_comp<<<1024, 256, 0, stream>>>(comp, Wc, bc, compEmb);
    if (NS == 4)      k_proj<4><<<768, 256, 0, stream>>>(pp, compEmb, W1, b1, P1);
    else if (NS == 2) k_proj<2><<<768, 256, 0, stream>>>(pp, compEmb, W1, b1, P1);
    else              k_proj<1><<<768, 256, 0, stream>>>(pp, compEmb, W1, b1, P1);
    k_pair<<<dim3(4, 8, 16), 256, 0, stream>>>(P1, C1, W2, b2, coords,
                                               out + 24576, out + 548864);
    k_misc<<<2048, 256, 0, stream>>>(dism, coords, out);
}

// Round 3
// 51.407 us; speedup vs baseline: 1.8524x; 1.1577x over previous
//
#include <hip/hip_runtime.h>
#include <hip/hip_bf16.h>
#include <cstddef>

// B=16, NC=128, NP=256, C=128, HID=256, MAXN=386, N_PROT=16384
// out layout (floats):
//  [0)       compound_coords_out : 6144
//  [6144)    compound_batch      : 2048
//  [8192)    pocket_coords_out   : 12288
//  [20480)   pocket_batch        : 4096
//  [24576)   y_pred              : 524288
//  [548864)  y_pred_by_coords    : 524288
//  [1073152) dis_map (copy)      : 524288
//  [1597440) keepNode_less_5     : 1
//
// Algebra: P1[6144][256] rows 0..4095 = prot[keep]@ (Wp@W1) + (bp@W1 + b1)
//          rows 4096..6143          = comp     @ (Wc@W1) + (bc@W1)
// logits[p,c] = sum_h relu(P1_p[h] + C1_c[h]) * W2[h] + b2

typedef __attribute__((ext_vector_type(8))) short short8v;      // 8 bf16
typedef __attribute__((ext_vector_type(4))) float f32x4;        // MFMA acc
typedef _Float16 half2v __attribute__((ext_vector_type(2)));
typedef _Float16 half8v __attribute__((ext_vector_type(8)));

__device__ __forceinline__ unsigned short f2bf(float x) {       // RNE f32->bf16
    unsigned int u = __float_as_uint(x);
    return (unsigned short)((u + 0x7fffu + ((u >> 16) & 1u)) >> 16);
}

__device__ __forceinline__ float dot8h(half8v r, half8v w, float acc) {
#if __has_builtin(__builtin_amdgcn_fdot2)
#pragma unroll
    for (int q = 0; q < 4; ++q) {
        half2v rq = {r[2 * q], r[2 * q + 1]};
        half2v wq = {w[2 * q], w[2 * q + 1]};
        acc = __builtin_amdgcn_fdot2(rq, wq, acc, false);
    }
#else
#pragma unroll
    for (int q = 0; q < 8; ++q) acc += (float)r[q] * (float)w[q];
#endif
    return acc;
}

// ws layout (bytes)
#define WS_WTP   0u          // 256*1280 bf16 = 655360
#define WS_WTC   655360u     // 256*64 bf16   = 32768
#define WS_BP1   688128u     // 256 f32
#define WS_BC1   689152u     // 256 f32
#define WS_W2H   690176u     // 256 fp16
#define WS_P1H   691200u     // 6144*256 fp16 = 3145728

// ---------------------------------------------------------------------------
// K1: fused weights. A-rows = [Wp(1280); Wc(56); bp; bc], K=128, out cols 256.
// blocks 0..159 -> WtP[j][k] bf16 ; 160..166 -> WtC ; 167 -> biases + W2h + pad
__global__ __launch_bounds__(256) void k_fusew(const float* __restrict__ Wp,
                                               const float* __restrict__ Wc,
                                               const float* __restrict__ bp,
                                               const float* __restrict__ bc,
                                               const float* __restrict__ W1,
                                               const float* __restrict__ b1,
                                               const float* __restrict__ W2,
                                               char* __restrict__ ws) {
    __shared__ float Al[8][128];
    const int tid = threadIdx.x, bid = blockIdx.x;
    const int row0 = bid * 8;
    {
        const int r = tid >> 5, k4 = (tid & 31) * 4;
        const int rg = row0 + r;
        float4 v = make_float4(0.f, 0.f, 0.f, 0.f);
        if (rg < 1280)       v = *reinterpret_cast<const float4*>(Wp + (size_t)rg * 128 + k4);
        else if (rg < 1336)  v = *reinterpret_cast<const float4*>(Wc + (size_t)(rg - 1280) * 128 + k4);
        else if (rg == 1336) v = *reinterpret_cast<const float4*>(bp + k4);
        else if (rg == 1337) v = *reinterpret_cast<const float4*>(bc + k4);
        *reinterpret_cast<float4*>(&Al[r][k4]) = v;
    }
    __syncthreads();
    float acc[8];
#pragma unroll
    for (int r = 0; r < 8; ++r) acc[r] = 0.f;
#pragma unroll 4
    for (int k4 = 0; k4 < 128; k4 += 4) {
        float w0 = W1[(k4 + 0) * 256 + tid];
        float w1 = W1[(k4 + 1) * 256 + tid];
        float w2 = W1[(k4 + 2) * 256 + tid];
        float w3 = W1[(k4 + 3) * 256 + tid];
#pragma unroll
        for (int r = 0; r < 8; ++r) {
            float4 a = *reinterpret_cast<const float4*>(&Al[r][k4]);
            acc[r] += a.x * w0 + a.y * w1 + a.z * w2 + a.w * w3;
        }
    }
    if (bid < 160) {
        unsigned int w[4];
#pragma unroll
        for (int q = 0; q < 4; ++q)
            w[q] = (unsigned int)f2bf(acc[2 * q]) | ((unsigned int)f2bf(acc[2 * q + 1]) << 16);
        unsigned short* WtP = (unsigned short*)(ws + WS_WTP);
        *reinterpret_cast<uint4*>(WtP + (size_t)tid * 1280 + row0) = make_uint4(w[0], w[1], w[2], w[3]);
    } else if (bid < 167) {
        unsigned int w[4];
#pragma unroll
        for (int q = 0; q < 4; ++q)
            w[q] = (unsigned int)f2bf(acc[2 * q]) | ((unsigned int)f2bf(acc[2 * q + 1]) << 16);
        unsigned short* WtC = (unsigned short*)(ws + WS_WTC);
        *reinterpret_cast<uint4*>(WtC + (size_t)tid * 64 + (row0 - 1280)) = make_uint4(w[0], w[1], w[2], w[3]);
    } else {
        ((float*)(ws + WS_BP1))[tid] = acc[0] + b1[tid];
        ((float*)(ws + WS_BC1))[tid] = acc[1];
        ((_Float16*)(ws + WS_W2H))[tid] = (_Float16)W2[tid];
        unsigned short* WtC = (unsigned short*)(ws + WS_WTC);
        *reinterpret_cast<uint4*>(WtC + (size_t)tid * 64 + 56) = make_uint4(0, 0, 0, 0);
    }
}

// ---------------------------------------------------------------------------
// K2: unified MFMA GEMM -> P1h[6144][256] fp16.
// m-tile 32, N=256, 4 waves (each 32x64). Pocket: K=1280 (20 iters, gather A).
// Compound: K=64 (1 iter, comp rows padded 56->64).
__global__ __launch_bounds__(256) void k_gemm(const float* __restrict__ prot,
                                              const int* __restrict__ keep,
                                              const float* __restrict__ comp,
                                              char* __restrict__ ws) {
    __shared__ __align__(16) char As[32 * 64 * 2];    // 4 KB
    __shared__ __align__(16) char Bs[256 * 64 * 2];   // 32 KB
    __shared__ int keepL[32];
    const int tid = threadIdx.x;
    const int l = tid & 63, wn = tid >> 6;
    const int l15 = l & 15, lg = l >> 4;
    const int m0 = blockIdx.x * 32;
    const bool pocket = (m0 < 4096);
    const int iters = pocket ? 20 : 1;
    const unsigned short* Bt = (const unsigned short*)(ws + (pocket ? WS_WTP : WS_WTC));
    const int bstride = pocket ? 1280 : 64;

    if (pocket && tid < 32) keepL[tid] = keep[m0 + tid];
    __syncthreads();

    f32x4 acc[2][4];
#pragma unroll
    for (int m = 0; m < 2; ++m)
#pragma unroll
        for (int n = 0; n < 4; ++n) acc[m][n] = (f32x4){0.f, 0.f, 0.f, 0.f};

    for (int it = 0; it < iters; ++it) {
        const int koff = it * 64;
        if (it) __syncthreads();
        // stage A: 32 rows x 64 k (f32 -> bf16), 2 float4-units/thread
#pragma unroll
        for (int u = 0; u < 2; ++u) {
            const int unit = tid + 256 * u;            // 0..511
            const int r = unit >> 4, kc = unit & 15;
            float4 v = make_float4(0.f, 0.f, 0.f, 0.f);
            if (pocket) {
                v = *reinterpret_cast<const float4*>(prot + (size_t)keepL[r] * 1280 + koff + kc * 4);
            } else if (kc < 14) {
                v = *reinterpret_cast<const float4*>(comp + (size_t)(m0 + r - 4096) * 56 + kc * 4);
            }
            const unsigned int lo = f2bf(v.x) | ((unsigned int)f2bf(v.y) << 16);
            const unsigned int hi = f2bf(v.z) | ((unsigned int)f2bf(v.w) << 16);
            const int wb = (r * 128 + kc * 8) ^ ((r & 7) << 4);
            *reinterpret_cast<uint2*>(As + wb) = make_uint2(lo, hi);
        }
        // stage B: 256 cols x 64 k bf16, 8 uint4-units/thread
#pragma unroll
        for (int u = 0; u < 8; ++u) {
            const int unit = tid + 256 * u;            // 0..2047
            const int col = unit >> 3, k8 = unit & 7;
            const uint4 v = *reinterpret_cast<const uint4*>(Bt + (size_t)col * bstride + koff + k8 * 8);
            const int wb = (col * 128 + k8 * 16) ^ ((col & 7) << 4);
            *reinterpret_cast<uint4*>(Bs + wb) = v;
        }
        __syncthreads();
#pragma unroll
        for (int ks = 0; ks < 2; ++ks) {
            const int kbyte = ks * 64 + lg * 16;
            short8v a[2], b[4];
#pragma unroll
            for (int m = 0; m < 2; ++m) {
                const int row = m * 16 + l15;
                a[m] = *reinterpret_cast<const short8v*>(As + ((row * 128 + kbyte) ^ ((row & 7) << 4)));
            }
#pragma unroll
            for (int n = 0; n < 4; ++n) {
                const int col = wn * 64 + n * 16 + l15;
                b[n] = *reinterpret_cast<const short8v*>(Bs + ((col * 128 + kbyte) ^ ((col & 7) << 4)));
            }
#pragma unroll
            for (int m = 0; m < 2; ++m)
#pragma unroll
                for (int n = 0; n < 4; ++n)
                    acc[m][n] = __builtin_amdgcn_mfma_f32_16x16x32_bf16(a[m], b[n], acc[m][n], 0, 0, 0);
        }
    }

    const float* bias = (const float*)(ws + (pocket ? WS_BP1 : WS_BC1));
    _Float16* P1h = (_Float16*)(ws + WS_P1H);
#pragma unroll
    for (int m = 0; m < 2; ++m)
#pragma unroll
        for (int n = 0; n < 4; ++n) {
            const int col = wn * 64 + n * 16 + l15;
            const float bb = bias[col];
#pragma unroll
            for (int i = 0; i < 4; ++i) {
                const int row = m0 + m * 16 + lg * 4 + i;
                P1h[(size_t)row * 256 + col] = (_Float16)(acc[m][n][i] + bb);
            }
        }
}

// ---------------------------------------------------------------------------
// K3: pair stage (fp16 packed) + fused misc outputs.
// Block tile: 32 p x 64 c for batch b. 256 thr: (pi,ci)=(tid>>4, tid&15),
// per-thread 2p x 4c. 32 h-iters of 8 halves. LDS XOR key = (row^(row>>2))&7.
__global__ __launch_bounds__(256) void k_pair(const char* __restrict__ ws,
                                              const float* __restrict__ b2,
                                              const float* __restrict__ coords,
                                              const float* __restrict__ dism,
                                              float* __restrict__ out) {
    __shared__ __align__(16) char Ph[32 * 512];    // 16 KB fp16 swizzled
    __shared__ __align__(16) char Ch[64 * 512];    // 32 KB
    __shared__ __align__(16) _Float16 W2l[256];
    __shared__ float pcs[32][3], ccs[64][3];
    const int tid = threadIdx.x;
    const int b = blockIdx.z, p0 = blockIdx.y * 32, c0 = blockIdx.x * 64;
    const _Float16* P1h = (const _Float16*)(ws + WS_P1H);

    // stage P: 1024 uint4 units (row 0..31, h8 0..31)
#pragma unroll
    for (int u = 0; u < 4; ++u) {
        const int unit = tid + 256 * u;
        const int row = unit >> 5, h8 = unit & 31;
        const uint4 v = *reinterpret_cast<const uint4*>(P1h + (size_t)(b * 256 + p0 + row) * 256 + h8 * 8);
        const int key = ((row ^ (row >> 2)) & 7) << 4;
        *reinterpret_cast<uint4*>(Ph + ((row * 512 + h8 * 16) ^ key)) = v;
    }
    // stage C: 2048 units (row 0..63)
#pragma unroll
    for (int u = 0; u < 8; ++u) {
        const int unit = tid + 256 * u;
        const int row = unit >> 5, h8 = unit & 31;
        const uint4 v = *reinterpret_cast<const uint4*>(P1h + (size_t)(4096 + b * 128 + c0 + row) * 256 + h8 * 8);
        const int key = ((row ^ (row >> 2)) & 7) << 4;
        *reinterpret_cast<uint4*>(Ch + ((row * 512 + h8 * 16) ^ key)) = v;
    }
    if (tid < 32) {
        *reinterpret_cast<uint4*>(W2l + tid * 8) =
            *reinterpret_cast<const uint4*>((const _Float16*)(ws + WS_W2H) + tid * 8);
        const float* s = coords + (size_t)(b * 386 + 130 + p0 + tid) * 3;
        pcs[tid][0] = s[0] / 5.0f; pcs[tid][1] = s[1] / 5.0f; pcs[tid][2] = s[2] / 5.0f;
    } else if (tid < 96) {
        const int t = tid - 32;
        const float* s = coords + (size_t)(b * 386 + 1 + c0 + t) * 3;
        ccs[t][0] = s[0] / 5.0f; ccs[t][1] = s[1] / 5.0f; ccs[t][2] = s[2] / 5.0f;
    }
    __syncthreads();

    const int pi = tid >> 4, ci = tid & 15;
    float acc[2][4] = {{0.f, 0.f, 0.f, 0.f}, {0.f, 0.f, 0.f, 0.f}};
#pragma unroll 4
    for (int h8 = 0; h8 < 32; ++h8) {
        const half8v wv = *reinterpret_cast<const half8v*>((const char*)W2l + h8 * 16);
        half8v pf[2], cf[4];
#pragma unroll
        for (int i = 0; i < 2; ++i) {
            const int row = pi * 2 + i;
            const int key = ((row ^ (row >> 2)) & 7) << 4;
            pf[i] = *reinterpret_cast<const half8v*>(Ph + ((row * 512 + h8 * 16) ^ key));
        }
#pragma unroll
        for (int j = 0; j < 4; ++j) {
            const int row = ci * 4 + j;
            const int key = ((row ^ (row >> 2)) & 7) << 4;
            cf[j] = *reinterpret_cast<const half8v*>(Ch + ((row * 512 + h8 * 16) ^ key));
        }
#pragma unroll
        for (int i = 0; i < 2; ++i)
#pragma unroll
            for (int j = 0; j < 4; ++j) {
                half8v s = pf[i] + cf[j];
                half8v r = __builtin_elementwise_max(s, (half8v)0);
                acc[i][j] = dot8h(r, wv, acc[i][j]);
            }
    }

    const float bb = b2[0];
#pragma unroll
    for (int i = 0; i < 2; ++i) {
        const int pr = pi * 2 + i;
        float4 y4, yc4;
        float* yp = &y4.x; float* yq = &yc4.x;
#pragma unroll
        for (int j = 0; j < 4; ++j) {
            const int cr = ci * 4 + j;
            const float logit = acc[i][j] + bb;
            yp[j] = 10.0f / (1.0f + expf(-logit));
            const float dx = pcs[pr][0] - ccs[cr][0];
            const float dy = pcs[pr][1] - ccs[cr][1];
            const float dz = pcs[pr][2] - ccs[cr][2];
            const float d = sqrtf(dx * dx + dy * dy + dz * dz + 1e-12f);
            yq[j] = fminf(fmaxf(d * 5.0f, 0.0f), 10.0f);
        }
        const size_t o = (size_t)(b * 256 + p0 + pr) * 128 + c0 + ci * 4;
        *reinterpret_cast<float4*>(out + 24576 + o) = y4;
        *reinterpret_cast<float4*>(out + 548864 + o) = yc4;
    }

    // fused misc: flat block id 0..255, global unit g handles 8 dis_map floats
    const int fb = blockIdx.x + 2 * (blockIdx.y + 8 * blockIdx.z);
    const int g = fb * 256 + tid;                    // 0..65535
    {
        const float4* src = reinterpret_cast<const float4*>(dism + (size_t)g * 8);
        float4* dst = reinterpret_cast<float4*>(out + 1073152 + (size_t)g * 8);
        dst[0] = src[0]; dst[1] = src[1];
    }
    if (g < 6144) {
        const int row = g / 3, d = g - row * 3;
        const int bb2 = row >> 7, c = row & 127;
        const float x = coords[(size_t)(bb2 * 386 + 1 + c) * 3 + d];
        out[g] = (x / 5.0f) * 5.0f;
    }
    if (g < 2048) out[6144 + g] = (float)(g >> 7);
    if (g < 12288) {
        const int row = g / 3, d = g - row * 3;
        const int bb2 = row >> 8, p = row & 255;
        const float x = coords[(size_t)(bb2 * 386 + 130 + p) * 3 + d];
        out[8192 + g] = (x / 5.0f) * 5.0f;
    }
    if (g < 4096) out[20480 + g] = (float)(g >> 8);
    if (g == 0) out[1597440] = 0.0f;
}

// ---------------------------------------------------------------------------
extern "C" void kernel_launch(void* const* d_in, const int* in_sizes, int n_in,
                              void* d_out, int out_size, void* d_ws, size_t ws_size,
                              hipStream_t stream) {
    const float* prot   = (const float*)d_in[0];
    const float* comp   = (const float*)d_in[1];
    const float* coords = (const float*)d_in[2];
    const float* dism   = (const float*)d_in[3];
    const int*   keep   = (const int*)d_in[4];
    const float* Wp = (const float*)d_in[7];
    const float* bp = (const float*)d_in[8];
    const float* Wc = (const float*)d_in[9];
    const float* bc = (const float*)d_in[10];
    const float* W1 = (const float*)d_in[11];
    const float* b1 = (const float*)d_in[12];
    const float* W2 = (const float*)d_in[13];
    const float* b2 = (const float*)d_in[14];
    float* out = (float*)d_out;
    char* ws = (char*)d_ws;

    k_fusew<<<168, 256, 0, stream>>>(Wp, Wc, bp, bc, W1, b1, W2, ws);
    k_gemm<<<192, 256, 0, stream>>>(prot, keep, comp, ws);
    k_pair<<<dim3(2, 8, 16), 256, 0, stream>>>(ws, b2, coords, dism, out);
}

// Round 4
// 48.343 us; speedup vs baseline: 1.9698x; 1.0634x over previous
//
#include <hip/hip_runtime.h>
#include <hip/hip_bf16.h>
#include <cstddef>

// B=16, NC=128, NP=256, C=128, HID=256, MAXN=386, N_PROT=16384
// out layout (floats):
//  [0)       compound_coords_out : 6144
//  [6144)    compound_batch      : 2048
//  [8192)    pocket_coords_out   : 12288
//  [20480)   pocket_batch        : 4096
//  [24576)   y_pred              : 524288
//  [548864)  y_pred_by_coords    : 524288
//  [1073152) dis_map (copy)      : 524288
//  [1597440) keepNode_less_5     : 1
//
// Algebra: P1[6144][256] rows 0..4095 = prot[keep]@ (Wp@W1) + (bp@W1 + b1)
//          rows 4096..6143          = comp     @ (Wc@W1) + (bc@W1)
// logits[p,c] = sum_h relu(P1_p[h] + C1_c[h]) * W2[h] + b2

typedef __attribute__((ext_vector_type(8))) short short8v;      // 8 bf16
typedef __attribute__((ext_vector_type(4))) float f32x4;        // MFMA acc
typedef _Float16 half2v __attribute__((ext_vector_type(2)));
typedef _Float16 half8v __attribute__((ext_vector_type(8)));

__device__ __forceinline__ unsigned int f2bf(float x) {         // RNE f32->bf16
    unsigned int u = __float_as_uint(x);
    return (u + 0x7fffu + ((u >> 16) & 1u)) >> 16;
}

__device__ __forceinline__ float dot8h(half8v r, half8v w, float acc) {
#if __has_builtin(__builtin_amdgcn_fdot2)
#pragma unroll
    for (int q = 0; q < 4; ++q) {
        half2v rq = {r[2 * q], r[2 * q + 1]};
        half2v wq = {w[2 * q], w[2 * q + 1]};
        acc = __builtin_amdgcn_fdot2(rq, wq, acc, false);
    }
#else
#pragma unroll
    for (int q = 0; q < 8; ++q) acc += (float)r[q] * (float)w[q];
#endif
    return acc;
}

// ws layout (bytes)
#define WS_WTP   0u          // 256*1280 bf16 = 655360
#define WS_WTC   655360u     // 256*64 bf16   = 32768
#define WS_BP1   688128u     // 256 f32
#define WS_BC1   689152u     // 256 f32
#define WS_W2H   690176u     // 256 fp16
#define WS_P1H   691200u     // 6144*256 fp16 = 3145728 (compound rows 4096+ used)
#define WS_PP0   3836928u    // 4096*256 f32 = 4194304 (pocket partial, ksplit 0 + bias)
#define WS_PP1   8031232u    // 4096*256 f32 = 4194304 (pocket partial, ksplit 1)

// ---------------------------------------------------------------------------
// K1: fused weights. A-rows = [Wp(1280); Wc(56); bp; bc], K=128, out cols 256.
// blocks 0..159 -> WtP[j][k] bf16 ; 160..166 -> WtC ; 167 -> biases + W2h + pad
__global__ __launch_bounds__(256) void k_fusew(const float* __restrict__ Wp,
                                               const float* __restrict__ Wc,
                                               const float* __restrict__ bp,
                                               const float* __restrict__ bc,
                                               const float* __restrict__ W1,
                                               const float* __restrict__ b1,
                                               const float* __restrict__ W2,
                                               char* __restrict__ ws) {
    __shared__ float Al[8][128];
    const int tid = threadIdx.x, bid = blockIdx.x;
    const int row0 = bid * 8;
    {
        const int r = tid >> 5, k4 = (tid & 31) * 4;
        const int rg = row0 + r;
        float4 v = make_float4(0.f, 0.f, 0.f, 0.f);
        if (rg < 1280)       v = *reinterpret_cast<const float4*>(Wp + (size_t)rg * 128 + k4);
        else if (rg < 1336)  v = *reinterpret_cast<const float4*>(Wc + (size_t)(rg - 1280) * 128 + k4);
        else if (rg == 1336) v = *reinterpret_cast<const float4*>(bp + k4);
        else if (rg == 1337) v = *reinterpret_cast<const float4*>(bc + k4);
        *reinterpret_cast<float4*>(&Al[r][k4]) = v;
    }
    __syncthreads();
    float acc[8];
#pragma unroll
    for (int r = 0; r < 8; ++r) acc[r] = 0.f;
#pragma unroll 4
    for (int k4 = 0; k4 < 128; k4 += 4) {
        float w0 = W1[(k4 + 0) * 256 + tid];
        float w1 = W1[(k4 + 1) * 256 + tid];
        float w2 = W1[(k4 + 2) * 256 + tid];
        float w3 = W1[(k4 + 3) * 256 + tid];
#pragma unroll
        for (int r = 0; r < 8; ++r) {
            float4 a = *reinterpret_cast<const float4*>(&Al[r][k4]);
            acc[r] += a.x * w0 + a.y * w1 + a.z * w2 + a.w * w3;
        }
    }
    if (bid < 160) {
        unsigned int w[4];
#pragma unroll
        for (int q = 0; q < 4; ++q)
            w[q] = f2bf(acc[2 * q]) | (f2bf(acc[2 * q + 1]) << 16);
        unsigned short* WtP = (unsigned short*)(ws + WS_WTP);
        *reinterpret_cast<uint4*>(WtP + (size_t)tid * 1280 + row0) = make_uint4(w[0], w[1], w[2], w[3]);
    } else if (bid < 167) {
        unsigned int w[4];
#pragma unroll
        for (int q = 0; q < 4; ++q)
            w[q] = f2bf(acc[2 * q]) | (f2bf(acc[2 * q + 1]) << 16);
        unsigned short* WtC = (unsigned short*)(ws + WS_WTC);
        *reinterpret_cast<uint4*>(WtC + (size_t)tid * 64 + (row0 - 1280)) = make_uint4(w[0], w[1], w[2], w[3]);
    } else {
        ((float*)(ws + WS_BP1))[tid] = acc[0] + b1[tid];
        ((float*)(ws + WS_BC1))[tid] = acc[1];
        ((_Float16*)(ws + WS_W2H))[tid] = (_Float16)W2[tid];
        unsigned short* WtC = (unsigned short*)(ws + WS_WTC);
        *reinterpret_cast<uint4*>(WtC + (size_t)tid * 64 + 56) = make_uint4(0, 0, 0, 0);
    }
}

// ---------------------------------------------------------------------------
// K2: unified MFMA GEMM. Pocket: split-K=2 (K=640/block, 10 iters), fp32
// partials -> pp0/pp1. Compound: K=64, 1 iter -> P1h fp16. Register-prefetch
// pipeline: iter t+1 global loads issue under iter t's ds_read+MFMA.
struct AB { float4 ra[2]; uint4 rb[8]; };

__device__ __forceinline__ void load_tile(AB& t, bool pocket, int koff,
                                          const float* __restrict__ prot,
                                          const float* __restrict__ comp,
                                          const int* keepL, int m0,
                                          const unsigned short* __restrict__ Bt,
                                          int bstride, int tid) {
#pragma unroll
    for (int u = 0; u < 2; ++u) {
        const int unit = tid + 256 * u;            // 0..511
        const int r = unit >> 4, kc = unit & 15;
        float4 v = make_float4(0.f, 0.f, 0.f, 0.f);
        if (pocket) {
            v = *reinterpret_cast<const float4*>(prot + (size_t)keepL[r] * 1280 + koff + kc * 4);
        } else if (kc < 14) {
            v = *reinterpret_cast<const float4*>(comp + (size_t)(m0 + r - 4096) * 56 + kc * 4);
        }
        t.ra[u] = v;
    }
#pragma unroll
    for (int u = 0; u < 8; ++u) {
        const int unit = tid + 256 * u;            // 0..2047
        const int col = unit >> 3, k8 = unit & 7;
        t.rb[u] = *reinterpret_cast<const uint4*>(Bt + (size_t)col * bstride + koff + k8 * 8);
    }
}

__device__ __forceinline__ void store_tile(const AB& t, char* As, char* Bs, int tid) {
#pragma unroll
    for (int u = 0; u < 2; ++u) {
        const int unit = tid + 256 * u;
        const int r = unit >> 4, kc = unit & 15;
        const float4 v = t.ra[u];
        const unsigned int lo = f2bf(v.x) | (f2bf(v.y) << 16);
        const unsigned int hi = f2bf(v.z) | (f2bf(v.w) << 16);
        const int wb = (r * 128 + kc * 8) ^ ((r & 7) << 4);
        *reinterpret_cast<uint2*>(As + wb) = make_uint2(lo, hi);
    }
#pragma unroll
    for (int u = 0; u < 8; ++u) {
        const int unit = tid + 256 * u;
        const int col = unit >> 3, k8 = unit & 7;
        const int wb = (col * 128 + k8 * 16) ^ ((col & 7) << 4);
        *reinterpret_cast<uint4*>(Bs + wb) = t.rb[u];
    }
}

__global__ __launch_bounds__(256) void k_gemm(const float* __restrict__ prot,
                                              const int* __restrict__ keep,
                                              const float* __restrict__ comp,
                                              char* __restrict__ ws) {
    __shared__ __align__(16) char As[32 * 64 * 2];    // 4 KB
    __shared__ __align__(16) char Bs[256 * 64 * 2];   // 32 KB
    __shared__ int keepL[32];
    const int tid = threadIdx.x;
    const int l = tid & 63, wn = tid >> 6;
    const int l15 = l & 15, lg = l >> 4;
    const int bid = blockIdx.x;
    const bool pocket = (bid < 256);
    const int ks = pocket ? (bid & 1) : 0;
    const int m0 = pocket ? ((bid >> 1) * 32) : (4096 + (bid - 256) * 32);
    const int koff0 = ks * 640;
    const int iters = pocket ? 10 : 1;
    const unsigned short* Bt = (const unsigned short*)(ws + (pocket ? WS_WTP : WS_WTC));
    const int bstride = pocket ? 1280 : 64;

    if (pocket && tid < 32) keepL[tid] = keep[m0 + tid];
    __syncthreads();

    f32x4 acc[2][4];
#pragma unroll
    for (int m = 0; m < 2; ++m)
#pragma unroll
        for (int n = 0; n < 4; ++n) acc[m][n] = (f32x4){0.f, 0.f, 0.f, 0.f};

    AB cur, nxt;
    load_tile(cur, pocket, koff0, prot, comp, keepL, m0, Bt, bstride, tid);

    for (int it = 0; it < iters; ++it) {
        if (it) __syncthreads();
        store_tile(cur, As, Bs, tid);
        __syncthreads();
        if (it + 1 < iters)
            load_tile(nxt, pocket, koff0 + (it + 1) * 64, prot, comp, keepL, m0, Bt, bstride, tid);
#pragma unroll
        for (int kstep = 0; kstep < 2; ++kstep) {
            const int kbyte = kstep * 64 + lg * 16;
            short8v a[2], b[4];
#pragma unroll
            for (int m = 0; m < 2; ++m) {
                const int row = m * 16 + l15;
                a[m] = *reinterpret_cast<const short8v*>(As + ((row * 128 + kbyte) ^ ((row & 7) << 4)));
            }
#pragma unroll
            for (int n = 0; n < 4; ++n) {
                const int col = wn * 64 + n * 16 + l15;
                b[n] = *reinterpret_cast<const short8v*>(Bs + ((col * 128 + kbyte) ^ ((col & 7) << 4)));
            }
#pragma unroll
            for (int m = 0; m < 2; ++m)
#pragma unroll
                for (int n = 0; n < 4; ++n)
                    acc[m][n] = __builtin_amdgcn_mfma_f32_16x16x32_bf16(a[m], b[n], acc[m][n], 0, 0, 0);
        }
        if (it + 1 < iters) cur = nxt;
    }

    if (pocket) {
        float* dst = (float*)(ws + (ks ? WS_PP1 : WS_PP0));
        const float* bias = (const float*)(ws + WS_BP1);
#pragma unroll
        for (int m = 0; m < 2; ++m)
#pragma unroll
            for (int n = 0; n < 4; ++n) {
                const int col = wn * 64 + n * 16 + l15;
                const float bb = (ks == 0) ? bias[col] : 0.f;
#pragma unroll
                for (int i = 0; i < 4; ++i) {
                    const int row = m0 + m * 16 + lg * 4 + i;
                    dst[((size_t)row << 8) + col] = acc[m][n][i] + bb;
                }
            }
    } else {
        const float* bias = (const float*)(ws + WS_BC1);
        _Float16* P1h = (_Float16*)(ws + WS_P1H);
#pragma unroll
        for (int m = 0; m < 2; ++m)
#pragma unroll
            for (int n = 0; n < 4; ++n) {
                const int col = wn * 64 + n * 16 + l15;
                const float bb = bias[col];
#pragma unroll
                for (int i = 0; i < 4; ++i) {
                    const int row = m0 + m * 16 + lg * 4 + i;
                    P1h[(size_t)row * 256 + col] = (_Float16)(acc[m][n][i] + bb);
                }
            }
    }
}

// ---------------------------------------------------------------------------
// K3: pair stage (fp16 packed) + fused misc outputs.
// Block tile: 32 p x 64 c for batch b. P-stage sums the two fp32 K-partials.
__global__ __launch_bounds__(256) void k_pair(const char* __restrict__ ws,
                                              const float* __restrict__ b2,
                                              const float* __restrict__ coords,
                                              const float* __restrict__ dism,
                                              float* __restrict__ out) {
    __shared__ __align__(16) char Ph[32 * 512];    // 16 KB fp16 swizzled
    __shared__ __align__(16) char Ch[64 * 512];    // 32 KB
    __shared__ __align__(16) _Float16 W2l[256];
    __shared__ float pcs[32][3], ccs[64][3];
    const int tid = threadIdx.x;
    const int b = blockIdx.z, p0 = blockIdx.y * 32, c0 = blockIdx.x * 64;
    const _Float16* P1h = (const _Float16*)(ws + WS_P1H);
    const float* pp0 = (const float*)(ws + WS_PP0);
    const float* pp1 = (const float*)(ws + WS_PP1);

    // stage P: 1024 units (row 0..31, h8 0..31); sum fp32 partials -> fp16
#pragma unroll
    for (int u = 0; u < 4; ++u) {
        const int unit = tid + 256 * u;
        const int row = unit >> 5, h8 = unit & 31;
        const size_t base = (((size_t)(b * 256 + p0 + row)) << 8) + h8 * 8;
        const float4 q0 = *reinterpret_cast<const float4*>(pp0 + base);
        const float4 q1 = *reinterpret_cast<const float4*>(pp0 + base + 4);
        const float4 r0 = *reinterpret_cast<const float4*>(pp1 + base);
        const float4 r1 = *reinterpret_cast<const float4*>(pp1 + base + 4);
        union { _Float16 h[8]; uint4 v; } U;
        U.h[0] = (_Float16)(q0.x + r0.x); U.h[1] = (_Float16)(q0.y + r0.y);
        U.h[2] = (_Float16)(q0.z + r0.z); U.h[3] = (_Float16)(q0.w + r0.w);
        U.h[4] = (_Float16)(q1.x + r1.x); U.h[5] = (_Float16)(q1.y + r1.y);
        U.h[6] = (_Float16)(q1.z + r1.z); U.h[7] = (_Float16)(q1.w + r1.w);
        const int key = ((row ^ (row >> 2)) & 7) << 4;
        *reinterpret_cast<uint4*>(Ph + ((row * 512 + h8 * 16) ^ key)) = U.v;
    }
    // stage C: 2048 units (row 0..63) from fp16 compound rows
#pragma unroll
    for (int u = 0; u < 8; ++u) {
        const int unit = tid + 256 * u;
        const int row = unit >> 5, h8 = unit & 31;
        const uint4 v = *reinterpret_cast<const uint4*>(P1h + (size_t)(4096 + b * 128 + c0 + row) * 256 + h8 * 8);
        const int key = ((row ^ (row >> 2)) & 7) << 4;
        *reinterpret_cast<uint4*>(Ch + ((row * 512 + h8 * 16) ^ key)) = v;
    }
    if (tid < 32) {
        *reinterpret_cast<uint4*>(W2l + tid * 8) =
            *reinterpret_cast<const uint4*>((const _Float16*)(ws + WS_W2H) + tid * 8);
        const float* s = coords + (size_t)(b * 386 + 130 + p0 + tid) * 3;
        pcs[tid][0] = s[0] / 5.0f; pcs[tid][1] = s[1] / 5.0f; pcs[tid][2] = s[2] / 5.0f;
    } else if (tid < 96) {
        const int t = tid - 32;
        const float* s = coords + (size_t)(b * 386 + 1 + c0 + t) * 3;
        ccs[t][0] = s[0] / 5.0f; ccs[t][1] = s[1] / 5.0f; ccs[t][2] = s[2] / 5.0f;
    }
    __syncthreads();

    const int pi = tid >> 4, ci = tid & 15;
    float acc[2][4] = {{0.f, 0.f, 0.f, 0.f}, {0.f, 0.f, 0.f, 0.f}};
#pragma unroll 4
    for (int h8 = 0; h8 < 32; ++h8) {
        const half8v wv = *reinterpret_cast<const half8v*>((const char*)W2l + h8 * 16);
        half8v pf[2], cf[4];
#pragma unroll
        for (int i = 0; i < 2; ++i) {
            const int row = pi * 2 + i;
            const int key = ((row ^ (row >> 2)) & 7) << 4;
            pf[i] = *reinterpret_cast<const half8v*>(Ph + ((row * 512 + h8 * 16) ^ key));
        }
#pragma unroll
        for (int j = 0; j < 4; ++j) {
            const int row = ci * 4 + j;
            const int key = ((row ^ (row >> 2)) & 7) << 4;
            cf[j] = *reinterpret_cast<const half8v*>(Ch + ((row * 512 + h8 * 16) ^ key));
        }
#pragma unroll
        for (int i = 0; i < 2; ++i)
#pragma unroll
            for (int j = 0; j < 4; ++j) {
                half8v s = pf[i] + cf[j];
                half8v r = __builtin_elementwise_max(s, (half8v)0);
                acc[i][j] = dot8h(r, wv, acc[i][j]);
            }
    }

    const float bb = b2[0];
#pragma unroll
    for (int i = 0; i < 2; ++i) {
        const int pr = pi * 2 + i;
        float4 y4, yc4;
        float* yp = &y4.x; float* yq = &yc4.x;
#pragma unroll
        for (int j = 0; j < 4; ++j) {
            const int cr = ci * 4 + j;
            const float logit = acc[i][j] + bb;
            yp[j] = 10.0f / (1.0f + expf(-logit));
            const float dx = pcs[pr][0] - ccs[cr][0];
            const float dy = pcs[pr][1] - ccs[cr][1];
            const float dz = pcs[pr][2] - ccs[cr][2];
            const float d = sqrtf(dx * dx + dy * dy + dz * dz + 1e-12f);
            yq[j] = fminf(fmaxf(d * 5.0f, 0.0f), 10.0f);
        }
        const size_t o = (size_t)(b * 256 + p0 + pr) * 128 + c0 + ci * 4;
        *reinterpret_cast<float4*>(out + 24576 + o) = y4;
        *reinterpret_cast<float4*>(out + 548864 + o) = yc4;
    }

    // fused misc: flat block id 0..255, global unit g handles 8 dis_map floats
    const int fb = blockIdx.x + 2 * (blockIdx.y + 8 * blockIdx.z);
    const int g = fb * 256 + tid;                    // 0..65535
    {
        const float4* src = reinterpret_cast<const float4*>(dism + (size_t)g * 8);
        float4* dst = reinterpret_cast<float4*>(out + 1073152 + (size_t)g * 8);
        dst[0] = src[0]; dst[1] = src[1];
    }
    if (g < 6144) {
        const int row = g / 3, d = g - row * 3;
        const int bb2 = row >> 7, c = row & 127;
        const float x = coords[(size_t)(bb2 * 386 + 1 + c) * 3 + d];
        out[g] = (x / 5.0f) * 5.0f;
    }
    if (g < 2048) out[6144 + g] = (float)(g >> 7);
    if (g < 12288) {
        const int row = g / 3, d = g - row * 3;
        const int bb2 = row >> 8, p = row & 255;
        const float x = coords[(size_t)(bb2 * 386 + 130 + p) * 3 + d];
        out[8192 + g] = (x / 5.0f) * 5.0f;
    }
    if (g < 4096) out[20480 + g] = (float)(g >> 8);
    if (g == 0) out[1597440] = 0.0f;
}

// ---------------------------------------------------------------------------
extern "C" void kernel_launch(void* const* d_in, const int* in_sizes, int n_in,
                              void* d_out, int out_size, void* d_ws, size_t ws_size,
                              hipStream_t stream) {
    const float* prot   = (const float*)d_in[0];
    const float* comp   = (const float*)d_in[1];
    const float* coords = (const float*)d_in[2];
    const float* dism   = (const float*)d_in[3];
    const int*   keep   = (const int*)d_in[4];
    const float* Wp = (const float*)d_in[7];
    const float* bp = (const float*)d_in[8];
    const float* Wc = (const float*)d_in[9];
    const float* bc = (const float*)d_in[10];
    const float* W1 = (const float*)d_in[11];
    const float* b1 = (const float*)d_in[12];
    const float* W2 = (const float*)d_in[13];
    const float* b2 = (const float*)d_in[14];
    float* out = (float*)d_out;
    char* ws = (char*)d_ws;

    k_fusew<<<168, 256, 0, stream>>>(Wp, Wc, bp, bc, W1, b1, W2, ws);
    k_gemm<<<320, 256, 0, stream>>>(prot, keep, comp, ws);
    k_pair<<<dim3(2, 8, 16), 256, 0, stream>>>(ws, b2, coords, dism, out);
}

// Round 5
// 43.828 us; speedup vs baseline: 2.1727x; 1.1030x over previous
//
#include <hip/hip_runtime.h>
#include <hip/hip_bf16.h>
#include <cstddef>

// B=16, NC=128, NP=256, C=128, HID=256, MAXN=386, N_PROT=16384
// out layout (floats):
//  [0)       compound_coords_out : 6144
//  [6144)    compound_batch      : 2048
//  [8192)    pocket_coords_out   : 12288
//  [20480)   pocket_batch        : 4096
//  [24576)   y_pred              : 524288
//  [548864)  y_pred_by_coords    : 524288
//  [1073152) dis_map (copy)      : 524288
//  [1597440) keepNode_less_5     : 1
//
// Algebra: P1[6144][256] rows 0..4095 = prot[keep]@ (Wp@W1) + (bp@W1 + b1)
//          rows 4096..6143          = comp     @ (Wc@W1) + (bc@W1)
// logits[p,c] = sum_h relu(P1_p[h] + C1_c[h]) * W2[h] + b2

typedef __attribute__((ext_vector_type(8))) short short8v;      // 8 bf16
typedef __attribute__((ext_vector_type(4))) float f32x4;        // MFMA acc
typedef _Float16 half2v __attribute__((ext_vector_type(2)));
typedef _Float16 half8v __attribute__((ext_vector_type(8)));

__device__ __forceinline__ unsigned int f2bf(float x) {         // RNE f32->bf16
    unsigned int u = __float_as_uint(x);
    return (u + 0x7fffu + ((u >> 16) & 1u)) >> 16;
}

__device__ __forceinline__ float dot8h(half8v r, half8v w, float acc) {
#if __has_builtin(__builtin_amdgcn_fdot2)
#pragma unroll
    for (int q = 0; q < 4; ++q) {
        half2v rq = {r[2 * q], r[2 * q + 1]};
        half2v wq = {w[2 * q], w[2 * q + 1]};
        acc = __builtin_amdgcn_fdot2(rq, wq, acc, false);
    }
#else
#pragma unroll
    for (int q = 0; q < 8; ++q) acc += (float)r[q] * (float)w[q];
#endif
    return acc;
}

// ws layout (bytes)
#define WS_WTP   0u          // 256*1280 bf16 = 655360
#define WS_WTC   655360u     // 256*64 bf16   = 32768
#define WS_BP1   688128u     // 256 f32
#define WS_BC1   689152u     // 256 f32
#define WS_W2H   690176u     // 256 fp16
#define WS_P1H   691200u     // 6144*256 fp16 = 3145728 (compound rows 4096+ used)
#define WS_PPH   3836928u    // 4 splits * 4096*256 fp16 (2097152 B each) = 8388608

// ---------------------------------------------------------------------------
// K1: fused weights (blocks 0..167) + misc outputs (blocks 168..423).
// Weight part: A-rows = [Wp(1280); Wc(56); bp; bc], K=128, out cols 256.
__global__ __launch_bounds__(256) void k_fusew(const float* __restrict__ Wp,
                                               const float* __restrict__ Wc,
                                               const float* __restrict__ bp,
                                               const float* __restrict__ bc,
                                               const float* __restrict__ W1,
                                               const float* __restrict__ b1,
                                               const float* __restrict__ W2,
                                               const float* __restrict__ coords,
                                               const float* __restrict__ dism,
                                               float* __restrict__ out,
                                               char* __restrict__ ws) {
    const int tid = threadIdx.x, bid = blockIdx.x;

    if (bid >= 168) {   // ---- misc outputs, independent of everything else
        const int g = (bid - 168) * 256 + tid;           // 0..65535
        {
            const float4* src = reinterpret_cast<const float4*>(dism + (size_t)g * 8);
            float4* dst = reinterpret_cast<float4*>(out + 1073152 + (size_t)g * 8);
            dst[0] = src[0]; dst[1] = src[1];
        }
        if (g < 6144) {
            const int row = g / 3, d = g - row * 3;
            const int bb2 = row >> 7, c = row & 127;
            const float x = coords[(size_t)(bb2 * 386 + 1 + c) * 3 + d];
            out[g] = (x / 5.0f) * 5.0f;
        }
        if (g < 2048) out[6144 + g] = (float)(g >> 7);
        if (g < 12288) {
            const int row = g / 3, d = g - row * 3;
            const int bb2 = row >> 8, p = row & 255;
            const float x = coords[(size_t)(bb2 * 386 + 130 + p) * 3 + d];
            out[8192 + g] = (x / 5.0f) * 5.0f;
        }
        if (g < 4096) out[20480 + g] = (float)(g >> 8);
        if (g == 0) out[1597440] = 0.0f;
        return;
    }

    __shared__ float Al[8][128];
    const int row0 = bid * 8;
    {
        const int r = tid >> 5, k4 = (tid & 31) * 4;
        const int rg = row0 + r;
        float4 v = make_float4(0.f, 0.f, 0.f, 0.f);
        if (rg < 1280)       v = *reinterpret_cast<const float4*>(Wp + (size_t)rg * 128 + k4);
        else if (rg < 1336)  v = *reinterpret_cast<const float4*>(Wc + (size_t)(rg - 1280) * 128 + k4);
        else if (rg == 1336) v = *reinterpret_cast<const float4*>(bp + k4);
        else if (rg == 1337) v = *reinterpret_cast<const float4*>(bc + k4);
        *reinterpret_cast<float4*>(&Al[r][k4]) = v;
    }
    __syncthreads();
    float acc[8];
#pragma unroll
    for (int r = 0; r < 8; ++r) acc[r] = 0.f;
#pragma unroll 4
    for (int k4 = 0; k4 < 128; k4 += 4) {
        float w0 = W1[(k4 + 0) * 256 + tid];
        float w1 = W1[(k4 + 1) * 256 + tid];
        float w2 = W1[(k4 + 2) * 256 + tid];
        float w3 = W1[(k4 + 3) * 256 + tid];
#pragma unroll
        for (int r = 0; r < 8; ++r) {
            float4 a = *reinterpret_cast<const float4*>(&Al[r][k4]);
            acc[r] += a.x * w0 + a.y * w1 + a.z * w2 + a.w * w3;
        }
    }
    if (bid < 160) {
        unsigned int w[4];
#pragma unroll
        for (int q = 0; q < 4; ++q)
            w[q] = f2bf(acc[2 * q]) | (f2bf(acc[2 * q + 1]) << 16);
        unsigned short* WtP = (unsigned short*)(ws + WS_WTP);
        *reinterpret_cast<uint4*>(WtP + (size_t)tid * 1280 + row0) = make_uint4(w[0], w[1], w[2], w[3]);
    } else if (bid < 167) {
        unsigned int w[4];
#pragma unroll
        for (int q = 0; q < 4; ++q)
            w[q] = f2bf(acc[2 * q]) | (f2bf(acc[2 * q + 1]) << 16);
        unsigned short* WtC = (unsigned short*)(ws + WS_WTC);
        *reinterpret_cast<uint4*>(WtC + (size_t)tid * 64 + (row0 - 1280)) = make_uint4(w[0], w[1], w[2], w[3]);
    } else {
        ((float*)(ws + WS_BP1))[tid] = acc[0] + b1[tid];
        ((float*)(ws + WS_BC1))[tid] = acc[1];
        ((_Float16*)(ws + WS_W2H))[tid] = (_Float16)W2[tid];
        unsigned short* WtC = (unsigned short*)(ws + WS_WTC);
        *reinterpret_cast<uint4*>(WtC + (size_t)tid * 64 + 56) = make_uint4(0, 0, 0, 0);
    }
}

// ---------------------------------------------------------------------------
// K2: unified MFMA GEMM. Pocket: split-K=4 (K=320/block, 5 iters), fp16
// partials. Compound: K=64, 1 iter -> P1h fp16. Register-prefetch pipeline.
struct AB { float4 ra[2]; uint4 rb[8]; };

__device__ __forceinline__ void load_tile(AB& t, bool pocket, int koff,
                                          const float* __restrict__ prot,
                                          const float* __restrict__ comp,
                                          const int* keepL, int m0,
                                          const unsigned short* __restrict__ Bt,
                                          int bstride, int tid) {
#pragma unroll
    for (int u = 0; u < 2; ++u) {
        const int unit = tid + 256 * u;            // 0..511
        const int r = unit >> 4, kc = unit & 15;
        float4 v = make_float4(0.f, 0.f, 0.f, 0.f);
        if (pocket) {
            v = *reinterpret_cast<const float4*>(prot + (size_t)keepL[r] * 1280 + koff + kc * 4);
        } else if (kc < 14) {
            v = *reinterpret_cast<const float4*>(comp + (size_t)(m0 + r - 4096) * 56 + kc * 4);
        }
        t.ra[u] = v;
    }
#pragma unroll
    for (int u = 0; u < 8; ++u) {
        const int unit = tid + 256 * u;            // 0..2047
        const int col = unit >> 3, k8 = unit & 7;
        t.rb[u] = *reinterpret_cast<const uint4*>(Bt + (size_t)col * bstride + koff + k8 * 8);
    }
}

__device__ __forceinline__ void store_tile(const AB& t, char* As, char* Bs, int tid) {
#pragma unroll
    for (int u = 0; u < 2; ++u) {
        const int unit = tid + 256 * u;
        const int r = unit >> 4, kc = unit & 15;
        const float4 v = t.ra[u];
        const unsigned int lo = f2bf(v.x) | (f2bf(v.y) << 16);
        const unsigned int hi = f2bf(v.z) | (f2bf(v.w) << 16);
        const int wb = (r * 128 + kc * 8) ^ ((r & 7) << 4);
        *reinterpret_cast<uint2*>(As + wb) = make_uint2(lo, hi);
    }
#pragma unroll
    for (int u = 0; u < 8; ++u) {
        const int unit = tid + 256 * u;
        const int col = unit >> 3, k8 = unit & 7;
        const int wb = (col * 128 + k8 * 16) ^ ((col & 7) << 4);
        *reinterpret_cast<uint4*>(Bs + wb) = t.rb[u];
    }
}

__global__ __launch_bounds__(256) void k_gemm(const float* __restrict__ prot,
                                              const int* __restrict__ keep,
                                              const float* __restrict__ comp,
                                              char* __restrict__ ws) {
    __shared__ __align__(16) char As[32 * 64 * 2];    // 4 KB
    __shared__ __align__(16) char Bs[256 * 64 * 2];   // 32 KB
    __shared__ int keepL[32];
    const int tid = threadIdx.x;
    const int l = tid & 63, wn = tid >> 6;
    const int l15 = l & 15, lg = l >> 4;
    const int bid = blockIdx.x;
    const bool pocket = (bid < 512);
    const int ks = pocket ? (bid & 3) : 0;
    const int m0 = pocket ? ((bid >> 2) * 32) : (4096 + (bid - 512) * 32);
    const int koff0 = ks * 320;
    const int iters = pocket ? 5 : 1;
    const unsigned short* Bt = (const unsigned short*)(ws + (pocket ? WS_WTP : WS_WTC));
    const int bstride = pocket ? 1280 : 64;

    if (pocket && tid < 32) keepL[tid] = keep[m0 + tid];
    __syncthreads();

    f32x4 acc[2][4];
#pragma unroll
    for (int m = 0; m < 2; ++m)
#pragma unroll
        for (int n = 0; n < 4; ++n) acc[m][n] = (f32x4){0.f, 0.f, 0.f, 0.f};

    AB cur, nxt;
    load_tile(cur, pocket, koff0, prot, comp, keepL, m0, Bt, bstride, tid);

    for (int it = 0; it < iters; ++it) {
        if (it) __syncthreads();
        store_tile(cur, As, Bs, tid);
        __syncthreads();
        if (it + 1 < iters)
            load_tile(nxt, pocket, koff0 + (it + 1) * 64, prot, comp, keepL, m0, Bt, bstride, tid);
#pragma unroll
        for (int kstep = 0; kstep < 2; ++kstep) {
            const int kbyte = kstep * 64 + lg * 16;
            short8v a[2], b[4];
#pragma unroll
            for (int m = 0; m < 2; ++m) {
                const int row = m * 16 + l15;
                a[m] = *reinterpret_cast<const short8v*>(As + ((row * 128 + kbyte) ^ ((row & 7) << 4)));
            }
#pragma unroll
            for (int n = 0; n < 4; ++n) {
                const int col = wn * 64 + n * 16 + l15;
                b[n] = *reinterpret_cast<const short8v*>(Bs + ((col * 128 + kbyte) ^ ((col & 7) << 4)));
            }
#pragma unroll
            for (int m = 0; m < 2; ++m)
#pragma unroll
                for (int n = 0; n < 4; ++n)
                    acc[m][n] = __builtin_amdgcn_mfma_f32_16x16x32_bf16(a[m], b[n], acc[m][n], 0, 0, 0);
        }
        if (it + 1 < iters) cur = nxt;
    }

    if (pocket) {
        _Float16* dst = (_Float16*)(ws + WS_PPH + (size_t)ks * 2097152u);
        const float* bias = (const float*)(ws + WS_BP1);
#pragma unroll
        for (int m = 0; m < 2; ++m)
#pragma unroll
            for (int n = 0; n < 4; ++n) {
                const int col = wn * 64 + n * 16 + l15;
                const float bb = (ks == 0) ? bias[col] : 0.f;
#pragma unroll
                for (int i = 0; i < 4; ++i) {
                    const int row = m0 + m * 16 + lg * 4 + i;
                    dst[((size_t)row << 8) + col] = (_Float16)(acc[m][n][i] + bb);
                }
            }
    } else {
        const float* bias = (const float*)(ws + WS_BC1);
        _Float16* P1h = (_Float16*)(ws + WS_P1H);
#pragma unroll
        for (int m = 0; m < 2; ++m)
#pragma unroll
            for (int n = 0; n < 4; ++n) {
                const int col = wn * 64 + n * 16 + l15;
                const float bb = bias[col];
#pragma unroll
                for (int i = 0; i < 4; ++i) {
                    const int row = m0 + m * 16 + lg * 4 + i;
                    P1h[(size_t)row * 256 + col] = (_Float16)(acc[m][n][i] + bb);
                }
            }
    }
}

// ---------------------------------------------------------------------------
// K3: pair stage (fp16 packed). Block tile: 32 p x 32 c for batch b
// (512 blocks -> 2 blocks/CU for TLP). P-stage sums the 4 fp16 K-partials.
__global__ __launch_bounds__(256) void k_pair(const char* __restrict__ ws,
                                              const float* __restrict__ b2,
                                              const float* __restrict__ coords,
                                              float* __restrict__ out) {
    __shared__ __align__(16) char Ph[32 * 512];    // 16 KB fp16 swizzled
    __shared__ __align__(16) char Ch[32 * 512];    // 16 KB
    __shared__ __align__(16) _Float16 W2l[256];
    __shared__ float pcs[32][3], ccs[32][3];
    const int tid = threadIdx.x;
    const int b = blockIdx.z, p0 = blockIdx.y * 32, c0 = blockIdx.x * 32;
    const _Float16* P1h = (const _Float16*)(ws + WS_P1H);
    const _Float16* pp = (const _Float16*)(ws + WS_PPH);

    // stage P: 1024 units (row 0..31, h8 0..31); sum 4 fp16 partials
#pragma unroll
    for (int u = 0; u < 4; ++u) {
        const int unit = tid + 256 * u;
        const int row = unit >> 5, h8 = unit & 31;
        const size_t base = (((size_t)(b * 256 + p0 + row)) << 8) + h8 * 8;
        const half8v s0 = *reinterpret_cast<const half8v*>(pp + base);
        const half8v s1 = *reinterpret_cast<const half8v*>(pp + 1048576u + base);
        const half8v s2 = *reinterpret_cast<const half8v*>(pp + 2097152u + base);
        const half8v s3 = *reinterpret_cast<const half8v*>(pp + 3145728u + base);
        const half8v t = (s0 + s1) + (s2 + s3);
        const int key = ((row ^ (row >> 2)) & 7) << 4;
        *reinterpret_cast<half8v*>(Ph + ((row * 512 + h8 * 16) ^ key)) = t;
    }
    // stage C: 1024 units from fp16 compound rows
#pragma unroll
    for (int u = 0; u < 4; ++u) {
        const int unit = tid + 256 * u;
        const int row = unit >> 5, h8 = unit & 31;
        const uint4 v = *reinterpret_cast<const uint4*>(P1h + (size_t)(4096 + b * 128 + c0 + row) * 256 + h8 * 8);
        const int key = ((row ^ (row >> 2)) & 7) << 4;
        *reinterpret_cast<uint4*>(Ch + ((row * 512 + h8 * 16) ^ key)) = v;
    }
    if (tid < 32) {
        *reinterpret_cast<uint4*>(W2l + tid * 8) =
            *reinterpret_cast<const uint4*>((const _Float16*)(ws + WS_W2H) + tid * 8);
        const float* s = coords + (size_t)(b * 386 + 130 + p0 + tid) * 3;
        pcs[tid][0] = s[0] / 5.0f; pcs[tid][1] = s[1] / 5.0f; pcs[tid][2] = s[2] / 5.0f;
    } else if (tid < 64) {
        const int t = tid - 32;
        const float* s = coords + (size_t)(b * 386 + 1 + c0 + t) * 3;
        ccs[t][0] = s[0] / 5.0f; ccs[t][1] = s[1] / 5.0f; ccs[t][2] = s[2] / 5.0f;
    }
    __syncthreads();

    const int pi = tid >> 4, ci = tid & 15;     // 2p x 2c per thread
    float acc[2][2] = {{0.f, 0.f}, {0.f, 0.f}};
#pragma unroll 4
    for (int h8 = 0; h8 < 32; ++h8) {
        const half8v wv = *reinterpret_cast<const half8v*>((const char*)W2l + h8 * 16);
        half8v pf[2], cf[2];
#pragma unroll
        for (int i = 0; i < 2; ++i) {
            const int row = pi * 2 + i;
            const int key = ((row ^ (row >> 2)) & 7) << 4;
            pf[i] = *reinterpret_cast<const half8v*>(Ph + ((row * 512 + h8 * 16) ^ key));
        }
#pragma unroll
        for (int j = 0; j < 2; ++j) {
            const int row = ci * 2 + j;
            const int key = ((row ^ (row >> 2)) & 7) << 4;
            cf[j] = *reinterpret_cast<const half8v*>(Ch + ((row * 512 + h8 * 16) ^ key));
        }
#pragma unroll
        for (int i = 0; i < 2; ++i)
#pragma unroll
            for (int j = 0; j < 2; ++j) {
                half8v s = pf[i] + cf[j];
                half8v r = __builtin_elementwise_max(s, (half8v)0);
                acc[i][j] = dot8h(r, wv, acc[i][j]);
            }
    }

    const float bb = b2[0];
#pragma unroll
    for (int i = 0; i < 2; ++i) {
        const int pr = pi * 2 + i;
        float2 y2, yc2;
        float* yp = &y2.x; float* yq = &yc2.x;
#pragma unroll
        for (int j = 0; j < 2; ++j) {
            const int cr = ci * 2 + j;
            const float logit = acc[i][j] + bb;
            yp[j] = 10.0f / (1.0f + expf(-logit));
            const float dx = pcs[pr][0] - ccs[cr][0];
            const float dy = pcs[pr][1] - ccs[cr][1];
            const float dz = pcs[pr][2] - ccs[cr][2];
            const float d = sqrtf(dx * dx + dy * dy + dz * dz + 1e-12f);
            yq[j] = fminf(fmaxf(d * 5.0f, 0.0f), 10.0f);
        }
        const size_t o = (size_t)(b * 256 + p0 + pr) * 128 + c0 + ci * 2;
        *reinterpret_cast<float2*>(out + 24576 + o) = y2;
        *reinterpret_cast<float2*>(out + 548864 + o) = yc2;
    }
}

// ---------------------------------------------------------------------------
extern "C" void kernel_launch(void* const* d_in, const int* in_sizes, int n_in,
                              void* d_out, int out_size, void* d_ws, size_t ws_size,
                              hipStream_t stream) {
    const float* prot   = (const float*)d_in[0];
    const float* comp   = (const float*)d_in[1];
    const float* coords = (const float*)d_in[2];
    const float* dism   = (const float*)d_in[3];
    const int*   keep   = (const int*)d_in[4];
    const float* Wp = (const float*)d_in[7];
    const float* bp = (const float*)d_in[8];
    const float* Wc = (const float*)d_in[9];
    const float* bc = (const float*)d_in[10];
    const float* W1 = (const float*)d_in[11];
    const float* b1 = (const float*)d_in[12];
    const float* W2 = (const float*)d_in[13];
    const float* b2 = (const float*)d_in[14];
    float* out = (float*)d_out;
    char* ws = (char*)d_ws;

    k_fusew<<<424, 256, 0, stream>>>(Wp, Wc, bp, bc, W1, b1, W2, coords, dism, out, ws);
    k_gemm<<<576, 256, 0, stream>>>(prot, keep, comp, ws);
    k_pair<<<dim3(4, 8, 16), 256, 0, stream>>>(ws, b2, coords, out);
}

// Round 6
// 39.804 us; speedup vs baseline: 2.3923x; 1.1011x over previous
//
#include <hip/hip_runtime.h>
#include <hip/hip_bf16.h>
#include <cstddef>

// B=16, NC=128, NP=256, C=128, HID=256, MAXN=386, N_PROT=16384
// out layout (floats):
//  [0)       compound_coords_out : 6144
//  [6144)    compound_batch      : 2048
//  [8192)    pocket_coords_out   : 12288
//  [20480)   pocket_batch        : 4096
//  [24576)   y_pred              : 524288
//  [548864)  y_pred_by_coords    : 524288
//  [1073152) dis_map (copy)      : 524288
//  [1597440) keepNode_less_5     : 1
//
// Algebra: P1[6144][256] rows 0..4095 = prot[keep]@ (Wp@W1) + (bp@W1 + b1)
//          rows 4096..6143          = comp     @ (Wc@W1) + (bc@W1)
// logits[p,c] = sum_h relu(P1_p[h] + C1_c[h]) * W2[h] + b2

typedef __attribute__((ext_vector_type(8))) short short8v;      // 8 bf16
typedef __attribute__((ext_vector_type(4))) float f32x4;        // MFMA acc
typedef _Float16 half2v __attribute__((ext_vector_type(2)));
typedef _Float16 half8v __attribute__((ext_vector_type(8)));

__device__ __forceinline__ unsigned int f2bf(float x) {         // RNE f32->bf16
    unsigned int u = __float_as_uint(x);
    return (u + 0x7fffu + ((u >> 16) & 1u)) >> 16;
}

__device__ __forceinline__ float dot8h(half8v r, half8v w, float acc) {
#if __has_builtin(__builtin_amdgcn_fdot2)
#pragma unroll
    for (int q = 0; q < 4; ++q) {
        half2v rq = {r[2 * q], r[2 * q + 1]};
        half2v wq = {w[2 * q], w[2 * q + 1]};
        acc = __builtin_amdgcn_fdot2(rq, wq, acc, false);
    }
#else
#pragma unroll
    for (int q = 0; q < 8; ++q) acc += (float)r[q] * (float)w[q];
#endif
    return acc;
}

// ws layout (bytes)
#define WS_WTP   0u          // 256*1280 bf16 = 655360
#define WS_WTC   655360u     // 256*64 bf16   = 32768
#define WS_BP1   688128u     // 256 f32
#define WS_BC1   689152u     // 256 f32
#define WS_W2H   690176u     // 256 fp16
#define WS_P1H   691200u     // 6144*256 fp16 = 3145728 (compound rows 4096+ used)
#define WS_PPH   3836928u    // 4 splits * 4096*256 fp16 (2097152 B each) = 8388608

// ---------------------------------------------------------------------------
// K1: fused weights (blocks 0..335, N-split x2) + misc outputs (336..591).
// Weight part: A-rows = [Wp(1280); Wc(56); bp; bc], K=128, out cols 256.
// Block (wb,nh): rows wb*8..+8, cols nh*128..+128. Thread: col=(tid&127)+nh*128,
// row-half rh=tid>>7 (4 rows each).
__global__ __launch_bounds__(256) void k_fusew(const float* __restrict__ Wp,
                                               const float* __restrict__ Wc,
                                               const float* __restrict__ bp,
                                               const float* __restrict__ bc,
                                               const float* __restrict__ W1,
                                               const float* __restrict__ b1,
                                               const float* __restrict__ W2,
                                               const float* __restrict__ coords,
                                               const float* __restrict__ dism,
                                               float* __restrict__ out,
                                               char* __restrict__ ws) {
    const int tid = threadIdx.x, bid = blockIdx.x;

    if (bid >= 336) {   // ---- misc outputs, independent of everything else
        const int g = (bid - 336) * 256 + tid;           // 0..65535
        {
            const float4* src = reinterpret_cast<const float4*>(dism + (size_t)g * 8);
            float4* dst = reinterpret_cast<float4*>(out + 1073152 + (size_t)g * 8);
            dst[0] = src[0]; dst[1] = src[1];
        }
        if (g < 6144) {
            const int row = g / 3, d = g - row * 3;
            const int bb2 = row >> 7, c = row & 127;
            const float x = coords[(size_t)(bb2 * 386 + 1 + c) * 3 + d];
            out[g] = (x / 5.0f) * 5.0f;
        }
        if (g < 2048) out[6144 + g] = (float)(g >> 7);
        if (g < 12288) {
            const int row = g / 3, d = g - row * 3;
            const int bb2 = row >> 8, p = row & 255;
            const float x = coords[(size_t)(bb2 * 386 + 130 + p) * 3 + d];
            out[8192 + g] = (x / 5.0f) * 5.0f;
        }
        if (g < 4096) out[20480 + g] = (float)(g >> 8);
        if (g == 0) out[1597440] = 0.0f;
        return;
    }

    __shared__ float Al[8][128];
    const int wb = bid >> 1, nh = bid & 1;
    const int row0 = wb * 8;
    {
        const int r = tid >> 5, k4 = (tid & 31) * 4;
        const int rg = row0 + r;
        float4 v = make_float4(0.f, 0.f, 0.f, 0.f);
        if (rg < 1280)       v = *reinterpret_cast<const float4*>(Wp + (size_t)rg * 128 + k4);
        else if (rg < 1336)  v = *reinterpret_cast<const float4*>(Wc + (size_t)(rg - 1280) * 128 + k4);
        else if (rg == 1336) v = *reinterpret_cast<const float4*>(bp + k4);
        else if (rg == 1337) v = *reinterpret_cast<const float4*>(bc + k4);
        *reinterpret_cast<float4*>(&Al[r][k4]) = v;
    }
    __syncthreads();
    const int col = (tid & 127) + nh * 128;
    const int rh = tid >> 7;                   // 0/1 -> rows rh*4 .. rh*4+3
    float acc[4] = {0.f, 0.f, 0.f, 0.f};
#pragma unroll 4
    for (int k4 = 0; k4 < 128; k4 += 4) {
        float w0 = W1[(k4 + 0) * 256 + col];
        float w1 = W1[(k4 + 1) * 256 + col];
        float w2 = W1[(k4 + 2) * 256 + col];
        float w3 = W1[(k4 + 3) * 256 + col];
#pragma unroll
        for (int r = 0; r < 4; ++r) {
            float4 a = *reinterpret_cast<const float4*>(&Al[rh * 4 + r][k4]);
            acc[r] += a.x * w0 + a.y * w1 + a.z * w2 + a.w * w3;
        }
    }
    if (wb < 160) {
        const unsigned int w0 = f2bf(acc[0]) | (f2bf(acc[1]) << 16);
        const unsigned int w1 = f2bf(acc[2]) | (f2bf(acc[3]) << 16);
        unsigned short* WtP = (unsigned short*)(ws + WS_WTP);
        *reinterpret_cast<uint2*>(WtP + (size_t)col * 1280 + row0 + rh * 4) = make_uint2(w0, w1);
    } else if (wb < 167) {
        const unsigned int w0 = f2bf(acc[0]) | (f2bf(acc[1]) << 16);
        const unsigned int w1 = f2bf(acc[2]) | (f2bf(acc[3]) << 16);
        unsigned short* WtC = (unsigned short*)(ws + WS_WTC);
        *reinterpret_cast<uint2*>(WtC + (size_t)col * 64 + (row0 - 1280) + rh * 4) = make_uint2(w0, w1);
    } else {            // wb == 167: rows 1336 (bp-fused), 1337 (bc-fused), pad
        if (rh == 0) {
            ((float*)(ws + WS_BP1))[col] = acc[0] + b1[col];
            ((float*)(ws + WS_BC1))[col] = acc[1];
        } else {
            ((_Float16*)(ws + WS_W2H))[col] = (_Float16)W2[col];
            unsigned short* WtC = (unsigned short*)(ws + WS_WTC);
            *reinterpret_cast<uint2*>(WtC + (size_t)col * 64 + 56) = make_uint2(0, 0);
            *reinterpret_cast<uint2*>(WtC + (size_t)col * 64 + 60) = make_uint2(0, 0);
        }
    }
}

// ---------------------------------------------------------------------------
// K2: unified MFMA GEMM, N-split x2 for occupancy (LDS 20 KB, ~4.5 blocks/CU).
// Pocket: 1024 blocks = 128 m-tiles x 4 K-splits x 2 N-halves; twins (same
// m,ks; other nh) are 8 block-ids apart -> same XCD under round-robin, so the
// duplicated A-gather hits L2. Compound: 128 blocks (64 m x 2 nh), K=64.
struct AB { float4 ra[2]; uint4 rb[4]; };

__device__ __forceinline__ void load_tile(AB& t, bool pocket, int koff, int nh,
                                          const float* __restrict__ prot,
                                          const float* __restrict__ comp,
                                          const int* keepL, int m0,
                                          const unsigned short* __restrict__ Bt,
                                          int bstride, int tid) {
#pragma unroll
    for (int u = 0; u < 2; ++u) {
        const int unit = tid + 256 * u;            // 0..511
        const int r = unit >> 4, kc = unit & 15;
        float4 v = make_float4(0.f, 0.f, 0.f, 0.f);
        if (pocket) {
            v = *reinterpret_cast<const float4*>(prot + (size_t)keepL[r] * 1280 + koff + kc * 4);
        } else if (kc < 14) {
            v = *reinterpret_cast<const float4*>(comp + (size_t)(m0 + r - 4096) * 56 + kc * 4);
        }
        t.ra[u] = v;
    }
#pragma unroll
    for (int u = 0; u < 4; ++u) {
        const int unit = tid + 256 * u;            // 0..1023
        const int col = unit >> 3, k8 = unit & 7;  // col: 0..127 local
        t.rb[u] = *reinterpret_cast<const uint4*>(Bt + (size_t)(nh * 128 + col) * bstride + koff + k8 * 8);
    }
}

__device__ __forceinline__ void store_tile(const AB& t, char* As, char* Bs, int tid) {
#pragma unroll
    for (int u = 0; u < 2; ++u) {
        const int unit = tid + 256 * u;
        const int r = unit >> 4, kc = unit & 15;
        const float4 v = t.ra[u];
        const unsigned int lo = f2bf(v.x) | (f2bf(v.y) << 16);
        const unsigned int hi = f2bf(v.z) | (f2bf(v.w) << 16);
        const int wb = (r * 128 + kc * 8) ^ ((r & 7) << 4);
        *reinterpret_cast<uint2*>(As + wb) = make_uint2(lo, hi);
    }
#pragma unroll
    for (int u = 0; u < 4; ++u) {
        const int unit = tid + 256 * u;
        const int col = unit >> 3, k8 = unit & 7;
        const int wb = (col * 128 + k8 * 16) ^ ((col & 7) << 4);
        *reinterpret_cast<uint4*>(Bs + wb) = t.rb[u];
    }
}

__global__ __launch_bounds__(256) void k_gemm(const float* __restrict__ prot,
                                              const int* __restrict__ keep,
                                              const float* __restrict__ comp,
                                              char* __restrict__ ws) {
    __shared__ __align__(16) char As[32 * 64 * 2];    // 4 KB
    __shared__ __align__(16) char Bs[128 * 64 * 2];   // 16 KB
    __shared__ int keepL[32];
    const int tid = threadIdx.x;
    const int l = tid & 63, wn = tid >> 6;            // wave: 32 rows x 32 cols
    const int l15 = l & 15, lg = l >> 4;
    const int bid = blockIdx.x;
    const bool pocket = (bid < 1024);
    int m0, ks, nh, iters, koff0, bstride;
    const unsigned short* Bt;
    if (pocket) {
        const int a = bid & 7, c = bid >> 4;
        nh = (bid >> 3) & 1;
        const int tile = a + (c << 3);                // 0..511, bijective
        m0 = (tile >> 2) * 32;
        ks = tile & 3;
        koff0 = ks * 320; iters = 5;
        Bt = (const unsigned short*)(ws + WS_WTP); bstride = 1280;
    } else {
        const int u = bid - 1024;                     // 0..127
        m0 = 4096 + (u >> 1) * 32;
        nh = u & 1; ks = 0;
        koff0 = 0; iters = 1;
        Bt = (const unsigned short*)(ws + WS_WTC); bstride = 64;
    }

    if (pocket && tid < 32) keepL[tid] = keep[m0 + tid];
    __syncthreads();

    f32x4 acc[2][2];
#pragma unroll
    for (int m = 0; m < 2; ++m)
#pragma unroll
        for (int n = 0; n < 2; ++n) acc[m][n] = (f32x4){0.f, 0.f, 0.f, 0.f};

    AB cur, nxt;
    load_tile(cur, pocket, koff0, nh, prot, comp, keepL, m0, Bt, bstride, tid);

    for (int it = 0; it < iters; ++it) {
        if (it) __syncthreads();
        store_tile(cur, As, Bs, tid);
        __syncthreads();
        if (it + 1 < iters)
            load_tile(nxt, pocket, koff0 + (it + 1) * 64, nh, prot, comp, keepL, m0, Bt, bstride, tid);
#pragma unroll
        for (int kstep = 0; kstep < 2; ++kstep) {
            const int kbyte = kstep * 64 + lg * 16;
            short8v a[2], b[2];
#pragma unroll
            for (int m = 0; m < 2; ++m) {
                const int row = m * 16 + l15;
                a[m] = *reinterpret_cast<const short8v*>(As + ((row * 128 + kbyte) ^ ((row & 7) << 4)));
            }
#pragma unroll
            for (int n = 0; n < 2; ++n) {
                const int col = wn * 32 + n * 16 + l15;
                b[n] = *reinterpret_cast<const short8v*>(Bs + ((col * 128 + kbyte) ^ ((col & 7) << 4)));
            }
#pragma unroll
            for (int m = 0; m < 2; ++m)
#pragma unroll
                for (int n = 0; n < 2; ++n)
                    acc[m][n] = __builtin_amdgcn_mfma_f32_16x16x32_bf16(a[m], b[n], acc[m][n], 0, 0, 0);
        }
        if (it + 1 < iters) cur = nxt;
    }

    if (pocket) {
        _Float16* dst = (_Float16*)(ws + WS_PPH + (size_t)ks * 2097152u);
        const float* bias = (const float*)(ws + WS_BP1);
#pragma unroll
        for (int m = 0; m < 2; ++m)
#pragma unroll
            for (int n = 0; n < 2; ++n) {
                const int col = nh * 128 + wn * 32 + n * 16 + l15;
                const float bb = (ks == 0) ? bias[col] : 0.f;
#pragma unroll
                for (int i = 0; i < 4; ++i) {
                    const int row = m0 + m * 16 + lg * 4 + i;
                    dst[((size_t)row << 8) + col] = (_Float16)(acc[m][n][i] + bb);
                }
            }
    } else {
        const float* bias = (const float*)(ws + WS_BC1);
        _Float16* P1h = (_Float16*)(ws + WS_P1H);
#pragma unroll
        for (int m = 0; m < 2; ++m)
#pragma unroll
            for (int n = 0; n < 2; ++n) {
                const int col = nh * 128 + wn * 32 + n * 16 + l15;
                const float bb = bias[col];
#pragma unroll
                for (int i = 0; i < 4; ++i) {
                    const int row = m0 + m * 16 + lg * 4 + i;
                    P1h[(size_t)row * 256 + col] = (_Float16)(acc[m][n][i] + bb);
                }
            }
    }
}

// ---------------------------------------------------------------------------
// K3: pair stage (fp16 packed). Block tile: 32 p x 32 c for batch b
// (512 blocks -> 2 blocks/CU for TLP). P-stage sums the 4 fp16 K-partials.
__global__ __launch_bounds__(256) void k_pair(const char* __restrict__ ws,
                                              const float* __restrict__ b2,
                                              const float* __restrict__ coords,
                                              float* __restrict__ out) {
    __shared__ __align__(16) char Ph[32 * 512];    // 16 KB fp16 swizzled
    __shared__ __align__(16) char Ch[32 * 512];    // 16 KB
    __shared__ __align__(16) _Float16 W2l[256];
    __shared__ float pcs[32][3], ccs[32][3];
    const int tid = threadIdx.x;
    const int b = blockIdx.z, p0 = blockIdx.y * 32, c0 = blockIdx.x * 32;
    const _Float16* P1h = (const _Float16*)(ws + WS_P1H);
    const _Float16* pp = (const _Float16*)(ws + WS_PPH);

    // stage P: 1024 units (row 0..31, h8 0..31); sum 4 fp16 partials
#pragma unroll
    for (int u = 0; u < 4; ++u) {
        const int unit = tid + 256 * u;
        const int row = unit >> 5, h8 = unit & 31;
        const size_t base = (((size_t)(b * 256 + p0 + row)) << 8) + h8 * 8;
        const half8v s0 = *reinterpret_cast<const half8v*>(pp + base);
        const half8v s1 = *reinterpret_cast<const half8v*>(pp + 1048576u + base);
        const half8v s2 = *reinterpret_cast<const half8v*>(pp + 2097152u + base);
        const half8v s3 = *reinterpret_cast<const half8v*>(pp + 3145728u + base);
        const half8v t = (s0 + s1) + (s2 + s3);
        const int key = ((row ^ (row >> 2)) & 7) << 4;
        *reinterpret_cast<half8v*>(Ph + ((row * 512 + h8 * 16) ^ key)) = t;
    }
    // stage C: 1024 units from fp16 compound rows
#pragma unroll
    for (int u = 0; u < 4; ++u) {
        const int unit = tid + 256 * u;
        const int row = unit >> 5, h8 = unit & 31;
        const uint4 v = *reinterpret_cast<const uint4*>(P1h + (size_t)(4096 + b * 128 + c0 + row) * 256 + h8 * 8);
        const int key = ((row ^ (row >> 2)) & 7) << 4;
        *reinterpret_cast<uint4*>(Ch + ((row * 512 + h8 * 16) ^ key)) = v;
    }
    if (tid < 32) {
        *reinterpret_cast<uint4*>(W2l + tid * 8) =
            *reinterpret_cast<const uint4*>((const _Float16*)(ws + WS_W2H) + tid * 8);
        const float* s = coords + (size_t)(b * 386 + 130 + p0 + tid) * 3;
        pcs[tid][0] = s[0] / 5.0f; pcs[tid][1] = s[1] / 5.0f; pcs[tid][2] = s[2] / 5.0f;
    } else if (tid < 64) {
        const int t = tid - 32;
        const float* s = coords + (size_t)(b * 386 + 1 + c0 + t) * 3;
        ccs[t][0] = s[0] / 5.0f; ccs[t][1] = s[1] / 5.0f; ccs[t][2] = s[2] / 5.0f;
    }
    __syncthreads();

    const int pi = tid >> 4, ci = tid & 15;     // 2p x 2c per thread
    float acc[2][2] = {{0.f, 0.f}, {0.f, 0.f}};
#pragma unroll 4
    for (int h8 = 0; h8 < 32; ++h8) {
        const half8v wv = *reinterpret_cast<const half8v*>((const char*)W2l + h8 * 16);
        half8v pf[2], cf[2];
#pragma unroll
        for (int i = 0; i < 2; ++i) {
            const int row = pi * 2 + i;
            const int key = ((row ^ (row >> 2)) & 7) << 4;
            pf[i] = *reinterpret_cast<const half8v*>(Ph + ((row * 512 + h8 * 16) ^ key));
        }
#pragma unroll
        for (int j = 0; j < 2; ++j) {
            const int row = ci * 2 + j;
            const int key = ((row ^ (row >> 2)) & 7) << 4;
            cf[j] = *reinterpret_cast<const half8v*>(Ch + ((row * 512 + h8 * 16) ^ key));
        }
#pragma unroll
        for (int i = 0; i < 2; ++i)
#pragma unroll
            for (int j = 0; j < 2; ++j) {
                half8v s = pf[i] + cf[j];
                half8v r = __builtin_elementwise_max(s, (half8v)0);
                acc[i][j] = dot8h(r, wv, acc[i][j]);
            }
    }

    const float bb = b2[0];
#pragma unroll
    for (int i = 0; i < 2; ++i) {
        const int pr = pi * 2 + i;
        float2 y2, yc2;
        float* yp = &y2.x; float* yq = &yc2.x;
#pragma unroll
        for (int j = 0; j < 2; ++j) {
            const int cr = ci * 2 + j;
            const float logit = acc[i][j] + bb;
            yp[j] = 10.0f / (1.0f + expf(-logit));
            const float dx = pcs[pr][0] - ccs[cr][0];
            const float dy = pcs[pr][1] - ccs[cr][1];
            const float dz = pcs[pr][2] - ccs[cr][2];
            const float d = sqrtf(dx * dx + dy * dy + dz * dz + 1e-12f);
            yq[j] = fminf(fmaxf(d * 5.0f, 0.0f), 10.0f);
        }
        const size_t o = (size_t)(b * 256 + p0 + pr) * 128 + c0 + ci * 2;
        *reinterpret_cast<float2*>(out + 24576 + o) = y2;
        *reinterpret_cast<float2*>(out + 548864 + o) = yc2;
    }
}

// ---------------------------------------------------------------------------
extern "C" void kernel_launch(void* const* d_in, const int* in_sizes, int n_in,
                              void* d_out, int out_size, void* d_ws, size_t ws_size,
                              hipStream_t stream) {
    const float* prot   = (const float*)d_in[0];
    const float* comp   = (const float*)d_in[1];
    const float* coords = (const float*)d_in[2];
    const float* dism   = (const float*)d_in[3];
    const int*   keep   = (const int*)d_in[4];
    const float* Wp = (const float*)d_in[7];
    const float* bp = (const float*)d_in[8];
    const float* Wc = (const float*)d_in[9];
    const float* bc = (const float*)d_in[10];
    const float* W1 = (const float*)d_in[11];
    const float* b1 = (const float*)d_in[12];
    const float* W2 = (const float*)d_in[13];
    const float* b2 = (const float*)d_in[14];
    float* out = (float*)d_out;
    char* ws = (char*)d_ws;

    k_fusew<<<592, 256, 0, stream>>>(Wp, Wc, bp, bc, W1, b1, W2, coords, dism, out, ws);
    k_gemm<<<1152, 256, 0, stream>>>(prot, keep, comp, ws);
    k_pair<<<dim3(4, 8, 16), 256, 0, stream>>>(ws, b2, coords, out);
}

// Round 7
// 39.278 us; speedup vs baseline: 2.4244x; 1.0134x over previous
//
#include <hip/hip_runtime.h>
#include <hip/hip_bf16.h>
#include <cstddef>

// B=16, NC=128, NP=256, C=128, HID=256, MAXN=386, N_PROT=16384
// out layout (floats):
//  [0)       compound_coords_out : 6144
//  [6144)    compound_batch      : 2048
//  [8192)    pocket_coords_out   : 12288
//  [20480)   pocket_batch        : 4096
//  [24576)   y_pred              : 524288
//  [548864)  y_pred_by_coords    : 524288
//  [1073152) dis_map (copy)      : 524288
//  [1597440) keepNode_less_5     : 1
//
// Algebra: P1[6144][256] rows 0..4095 = prot[keep]@ (Wp@W1) + (bp@W1 + b1)
//          rows 4096..6143          = comp     @ (Wc@W1) + (bc@W1)
// logits[p,c] = sum_h relu(P1_p[h] + C1_c[h]) * W2[h] + b2

typedef __attribute__((ext_vector_type(8))) short short8v;      // 8 bf16
typedef __attribute__((ext_vector_type(4))) float f32x4;        // MFMA acc
typedef _Float16 half2v __attribute__((ext_vector_type(2)));
typedef _Float16 half8v __attribute__((ext_vector_type(8)));

__device__ __forceinline__ unsigned int f2bf(float x) {         // RNE f32->bf16
    unsigned int u = __float_as_uint(x);
    return (u + 0x7fffu + ((u >> 16) & 1u)) >> 16;
}

__device__ __forceinline__ float dot8h(half8v r, half8v w, float acc) {
#if __has_builtin(__builtin_amdgcn_fdot2)
#pragma unroll
    for (int q = 0; q < 4; ++q) {
        half2v rq = {r[2 * q], r[2 * q + 1]};
        half2v wq = {w[2 * q], w[2 * q + 1]};
        acc = __builtin_amdgcn_fdot2(rq, wq, acc, false);
    }
#else
#pragma unroll
    for (int q = 0; q < 8; ++q) acc += (float)r[q] * (float)w[q];
#endif
    return acc;
}

// ws layout (bytes)
#define WS_WTP   0u          // 256*1280 bf16 = 655360
#define WS_WTC   655360u     // 256*64 bf16   = 32768
#define WS_BP1   688128u     // 256 f32
#define WS_BC1   689152u     // 256 f32
#define WS_W2H   690176u     // 256 fp16
#define WS_P1H   691200u     // 6144*256 fp16 = 3145728 (compound rows 4096+ used)
#define WS_PPH   3836928u    // 4 splits * 4096*256 fp16 (2097152 B each) = 8388608

// ---------------------------------------------------------------------------
// K1: fused weights (blocks 0..335, N-split x2) + misc outputs (336..591).
__global__ __launch_bounds__(256) void k_fusew(const float* __restrict__ Wp,
                                               const float* __restrict__ Wc,
                                               const float* __restrict__ bp,
                                               const float* __restrict__ bc,
                                               const float* __restrict__ W1,
                                               const float* __restrict__ b1,
                                               const float* __restrict__ W2,
                                               const float* __restrict__ coords,
                                               const float* __restrict__ dism,
                                               float* __restrict__ out,
                                               char* __restrict__ ws) {
    const int tid = threadIdx.x, bid = blockIdx.x;

    if (bid >= 336) {   // ---- misc outputs, independent of everything else
        const int g = (bid - 336) * 256 + tid;           // 0..65535
        {
            const float4* src = reinterpret_cast<const float4*>(dism + (size_t)g * 8);
            float4* dst = reinterpret_cast<float4*>(out + 1073152 + (size_t)g * 8);
            dst[0] = src[0]; dst[1] = src[1];
        }
        if (g < 6144) {
            const int row = g / 3, d = g - row * 3;
            const int bb2 = row >> 7, c = row & 127;
            const float x = coords[(size_t)(bb2 * 386 + 1 + c) * 3 + d];
            out[g] = (x / 5.0f) * 5.0f;
        }
        if (g < 2048) out[6144 + g] = (float)(g >> 7);
        if (g < 12288) {
            const int row = g / 3, d = g - row * 3;
            const int bb2 = row >> 8, p = row & 255;
            const float x = coords[(size_t)(bb2 * 386 + 130 + p) * 3 + d];
            out[8192 + g] = (x / 5.0f) * 5.0f;
        }
        if (g < 4096) out[20480 + g] = (float)(g >> 8);
        if (g == 0) out[1597440] = 0.0f;
        return;
    }

    __shared__ float Al[8][128];
    const int wb = bid >> 1, nh = bid & 1;
    const int row0 = wb * 8;
    {
        const int r = tid >> 5, k4 = (tid & 31) * 4;
        const int rg = row0 + r;
        float4 v = make_float4(0.f, 0.f, 0.f, 0.f);
        if (rg < 1280)       v = *reinterpret_cast<const float4*>(Wp + (size_t)rg * 128 + k4);
        else if (rg < 1336)  v = *reinterpret_cast<const float4*>(Wc + (size_t)(rg - 1280) * 128 + k4);
        else if (rg == 1336) v = *reinterpret_cast<const float4*>(bp + k4);
        else if (rg == 1337) v = *reinterpret_cast<const float4*>(bc + k4);
        *reinterpret_cast<float4*>(&Al[r][k4]) = v;
    }
    __syncthreads();
    const int col = (tid & 127) + nh * 128;
    const int rh = tid >> 7;                   // 0/1 -> rows rh*4 .. rh*4+3
    float acc[4] = {0.f, 0.f, 0.f, 0.f};
#pragma unroll 4
    for (int k4 = 0; k4 < 128; k4 += 4) {
        float w0 = W1[(k4 + 0) * 256 + col];
        float w1 = W1[(k4 + 1) * 256 + col];
        float w2 = W1[(k4 + 2) * 256 + col];
        float w3 = W1[(k4 + 3) * 256 + col];
#pragma unroll
        for (int r = 0; r < 4; ++r) {
            float4 a = *reinterpret_cast<const float4*>(&Al[rh * 4 + r][k4]);
            acc[r] += a.x * w0 + a.y * w1 + a.z * w2 + a.w * w3;
        }
    }
    if (wb < 160) {
        const unsigned int w0 = f2bf(acc[0]) | (f2bf(acc[1]) << 16);
        const unsigned int w1 = f2bf(acc[2]) | (f2bf(acc[3]) << 16);
        unsigned short* WtP = (unsigned short*)(ws + WS_WTP);
        *reinterpret_cast<uint2*>(WtP + (size_t)col * 1280 + row0 + rh * 4) = make_uint2(w0, w1);
    } else if (wb < 167) {
        const unsigned int w0 = f2bf(acc[0]) | (f2bf(acc[1]) << 16);
        const unsigned int w1 = f2bf(acc[2]) | (f2bf(acc[3]) << 16);
        unsigned short* WtC = (unsigned short*)(ws + WS_WTC);
        *reinterpret_cast<uint2*>(WtC + (size_t)col * 64 + (row0 - 1280) + rh * 4) = make_uint2(w0, w1);
    } else {            // wb == 167: rows 1336 (bp-fused), 1337 (bc-fused), pad
        if (rh == 0) {
            ((float*)(ws + WS_BP1))[col] = acc[0] + b1[col];
            ((float*)(ws + WS_BC1))[col] = acc[1];
        } else {
            ((_Float16*)(ws + WS_W2H))[col] = (_Float16)W2[col];
            unsigned short* WtC = (unsigned short*)(ws + WS_WTC);
            *reinterpret_cast<uint2*>(WtC + (size_t)col * 64 + 56) = make_uint2(0, 0);
            *reinterpret_cast<uint2*>(WtC + (size_t)col * 64 + 60) = make_uint2(0, 0);
        }
    }
}

// ---------------------------------------------------------------------------
// K2: unified MFMA GEMM, 512 threads (8 waves), 32m x 256n per block.
// Pocket: 512 blocks = 128 m-tiles x 4 K-splits (K=320, 5 iters), fp16
// partials. Compound: 64 blocks, K=64, 1 iter. 2-deep register prefetch:
// iter t+2's global loads issue under iter t's ds_read+MFMA.
struct AB { float4 ra; uint4 rb[4]; };

__device__ __forceinline__ void load_tile(AB& t, bool pocket, int koff,
                                          const float* __restrict__ prot,
                                          const float* __restrict__ comp,
                                          const int* keepL, int m0,
                                          const unsigned short* __restrict__ Bt,
                                          int bstride, int tid) {
    {
        const int r = tid >> 4, kc = tid & 15;     // 32 rows x 16 f32x4 chunks
        float4 v = make_float4(0.f, 0.f, 0.f, 0.f);
        if (pocket) {
            v = *reinterpret_cast<const float4*>(prot + (size_t)keepL[r] * 1280 + koff + kc * 4);
        } else if (kc < 14) {
            v = *reinterpret_cast<const float4*>(comp + (size_t)(m0 + r - 4096) * 56 + kc * 4);
        }
        t.ra = v;
    }
#pragma unroll
    for (int u = 0; u < 4; ++u) {
        const int unit = tid + 512 * u;            // 0..2047
        const int col = unit >> 3, k8 = unit & 7;  // 256 cols x 8 k8-chunks
        t.rb[u] = *reinterpret_cast<const uint4*>(Bt + (size_t)col * bstride + koff + k8 * 8);
    }
}

__device__ __forceinline__ void store_tile(const AB& t, char* As, char* Bs, int tid) {
    {
        const int r = tid >> 4, kc = tid & 15;
        const float4 v = t.ra;
        const unsigned int lo = f2bf(v.x) | (f2bf(v.y) << 16);
        const unsigned int hi = f2bf(v.z) | (f2bf(v.w) << 16);
        const int wb = (r * 128 + kc * 8) ^ ((r & 7) << 4);
        *reinterpret_cast<uint2*>(As + wb) = make_uint2(lo, hi);
    }
#pragma unroll
    for (int u = 0; u < 4; ++u) {
        const int unit = tid + 512 * u;
        const int col = unit >> 3, k8 = unit & 7;
        const int wb = (col * 128 + k8 * 16) ^ ((col & 7) << 4);
        *reinterpret_cast<uint4*>(Bs + wb) = t.rb[u];
    }
}

__global__ __launch_bounds__(512) void k_gemm(const float* __restrict__ prot,
                                              const int* __restrict__ keep,
                                              const float* __restrict__ comp,
                                              char* __restrict__ ws) {
    __shared__ __align__(16) char As[32 * 64 * 2];    // 4 KB
    __shared__ __align__(16) char Bs[256 * 64 * 2];   // 32 KB
    __shared__ int keepL[32];
    const int tid = threadIdx.x;
    const int l = tid & 63, wid = tid >> 6;
    const int wm = wid & 1, wn = wid >> 1;            // wave: 16 rows x 64 cols
    const int l15 = l & 15, lg = l >> 4;
    const int bid = blockIdx.x;
    const bool pocket = (bid < 512);
    int m0, ks, iters, koff0, bstride;
    const unsigned short* Bt;
    if (pocket) {
        m0 = (bid >> 2) * 32;
        ks = bid & 3;
        koff0 = ks * 320; iters = 5;
        Bt = (const unsigned short*)(ws + WS_WTP); bstride = 1280;
    } else {
        m0 = 4096 + (bid - 512) * 32;
        ks = 0; koff0 = 0; iters = 1;
        Bt = (const unsigned short*)(ws + WS_WTC); bstride = 64;
    }

    if (pocket && tid < 32) keepL[tid] = keep[m0 + tid];
    __syncthreads();

    f32x4 acc[4];
#pragma unroll
    for (int n = 0; n < 4; ++n) acc[n] = (f32x4){0.f, 0.f, 0.f, 0.f};

    AB t0, t1, t2;
    load_tile(t0, pocket, koff0, prot, comp, keepL, m0, Bt, bstride, tid);
    if (iters > 1)
        load_tile(t1, pocket, koff0 + 64, prot, comp, keepL, m0, Bt, bstride, tid);

    for (int it = 0; it < iters; ++it) {
        if (it) __syncthreads();
        store_tile(t0, As, Bs, tid);
        __syncthreads();
        if (it + 2 < iters)
            load_tile(t2, pocket, koff0 + (it + 2) * 64, prot, comp, keepL, m0, Bt, bstride, tid);
#pragma unroll
        for (int kstep = 0; kstep < 2; ++kstep) {
            const int kbyte = kstep * 64 + lg * 16;
            short8v a, b[4];
            {
                const int row = wm * 16 + l15;
                a = *reinterpret_cast<const short8v*>(As + ((row * 128 + kbyte) ^ ((row & 7) << 4)));
            }
#pragma unroll
            for (int n = 0; n < 4; ++n) {
                const int col = wn * 64 + n * 16 + l15;
                b[n] = *reinterpret_cast<const short8v*>(Bs + ((col * 128 + kbyte) ^ ((col & 7) << 4)));
            }
#pragma unroll
            for (int n = 0; n < 4; ++n)
                acc[n] = __builtin_amdgcn_mfma_f32_16x16x32_bf16(a, b[n], acc[n], 0, 0, 0);
        }
        if (it + 1 < iters) { t0 = t1; t1 = t2; }
    }

    if (pocket) {
        _Float16* dst = (_Float16*)(ws + WS_PPH + (size_t)ks * 2097152u);
        const float* bias = (const float*)(ws + WS_BP1);
#pragma unroll
        for (int n = 0; n < 4; ++n) {
            const int col = wn * 64 + n * 16 + l15;
            const float bb = (ks == 0) ? bias[col] : 0.f;
#pragma unroll
            for (int i = 0; i < 4; ++i) {
                const int row = m0 + wm * 16 + lg * 4 + i;
                dst[((size_t)row << 8) + col] = (_Float16)(acc[n][i] + bb);
            }
        }
    } else {
        const float* bias = (const float*)(ws + WS_BC1);
        _Float16* P1h = (_Float16*)(ws + WS_P1H);
#pragma unroll
        for (int n = 0; n < 4; ++n) {
            const int col = wn * 64 + n * 16 + l15;
            const float bb = bias[col];
#pragma unroll
            for (int i = 0; i < 4; ++i) {
                const int row = m0 + wm * 16 + lg * 4 + i;
                P1h[(size_t)row * 256 + col] = (_Float16)(acc[n][i] + bb);
            }
        }
    }
}

// ---------------------------------------------------------------------------
// K3: pair stage (fp16 packed). Block tile: 32 p x 64 c (I=2, J=4 per thread)
// -> 28 LDS-read instr/output (vs 40 at 32x32) and pph re-read halved.
// 256 blocks = 1 block/CU. P-stage sums the 4 fp16 K-partials.
__global__ __launch_bounds__(256) void k_pair(const char* __restrict__ ws,
                                              const float* __restrict__ b2,
                                              const float* __restrict__ coords,
                                              float* __restrict__ out) {
    __shared__ __align__(16) char Ph[32 * 512];    // 16 KB fp16 swizzled
    __shared__ __align__(16) char Ch[64 * 512];    // 32 KB
    __shared__ __align__(16) _Float16 W2l[256];
    __shared__ float pcs[32][3], ccs[64][3];
    const int tid = threadIdx.x;
    const int b = blockIdx.z, p0 = blockIdx.y * 32, c0 = blockIdx.x * 64;
    const _Float16* P1h = (const _Float16*)(ws + WS_P1H);
    const _Float16* pp = (const _Float16*)(ws + WS_PPH);

    // stage P: 1024 units (row 0..31, h8 0..31); sum 4 fp16 partials
#pragma unroll
    for (int u = 0; u < 4; ++u) {
        const int unit = tid + 256 * u;
        const int row = unit >> 5, h8 = unit & 31;
        const size_t base = (((size_t)(b * 256 + p0 + row)) << 8) + h8 * 8;
        const half8v s0 = *reinterpret_cast<const half8v*>(pp + base);
        const half8v s1 = *reinterpret_cast<const half8v*>(pp + 1048576u + base);
        const half8v s2 = *reinterpret_cast<const half8v*>(pp + 2097152u + base);
        const half8v s3 = *reinterpret_cast<const half8v*>(pp + 3145728u + base);
        const half8v t = (s0 + s1) + (s2 + s3);
        const int key = ((row ^ (row >> 2)) & 7) << 4;
        *reinterpret_cast<half8v*>(Ph + ((row * 512 + h8 * 16) ^ key)) = t;
    }
    // stage C: 2048 units (row 0..63) from fp16 compound rows
#pragma unroll
    for (int u = 0; u < 8; ++u) {
        const int unit = tid + 256 * u;
        const int row = unit >> 5, h8 = unit & 31;
        const uint4 v = *reinterpret_cast<const uint4*>(P1h + (size_t)(4096 + b * 128 + c0 + row) * 256 + h8 * 8);
        const int key = ((row ^ (row >> 2)) & 7) << 4;
        *reinterpret_cast<uint4*>(Ch + ((row * 512 + h8 * 16) ^ key)) = v;
    }
    if (tid < 32) {
        *reinterpret_cast<uint4*>(W2l + tid * 8) =
            *reinterpret_cast<const uint4*>((const _Float16*)(ws + WS_W2H) + tid * 8);
        const float* s = coords + (size_t)(b * 386 + 130 + p0 + tid) * 3;
        pcs[tid][0] = s[0] / 5.0f; pcs[tid][1] = s[1] / 5.0f; pcs[tid][2] = s[2] / 5.0f;
    } else if (tid < 96) {
        const int t = tid - 32;
        const float* s = coords + (size_t)(b * 386 + 1 + c0 + t) * 3;
        ccs[t][0] = s[0] / 5.0f; ccs[t][1] = s[1] / 5.0f; ccs[t][2] = s[2] / 5.0f;
    }
    __syncthreads();

    const int pi = tid >> 4, ci = tid & 15;     // 2p x 4c per thread
    float acc[2][4] = {{0.f, 0.f, 0.f, 0.f}, {0.f, 0.f, 0.f, 0.f}};
#pragma unroll 4
    for (int h8 = 0; h8 < 32; ++h8) {
        const half8v wv = *reinterpret_cast<const half8v*>((const char*)W2l + h8 * 16);
        half8v pf[2], cf[4];
#pragma unroll
        for (int i = 0; i < 2; ++i) {
            const int row = pi * 2 + i;
            const int key = ((row ^ (row >> 2)) & 7) << 4;
            pf[i] = *reinterpret_cast<const half8v*>(Ph + ((row * 512 + h8 * 16) ^ key));
        }
#pragma unroll
        for (int j = 0; j < 4; ++j) {
            const int row = ci * 4 + j;
            const int key = ((row ^ (row >> 2)) & 7) << 4;
            cf[j] = *reinterpret_cast<const half8v*>(Ch + ((row * 512 + h8 * 16) ^ key));
        }
#pragma unroll
        for (int i = 0; i < 2; ++i)
#pragma unroll
            for (int j = 0; j < 4; ++j) {
                half8v s = pf[i] + cf[j];
                half8v r = __builtin_elementwise_max(s, (half8v)0);
                acc[i][j] = dot8h(r, wv, acc[i][j]);
            }
    }

    const float bb = b2[0];
#pragma unroll
    for (int i = 0; i < 2; ++i) {
        const int pr = pi * 2 + i;
        float4 y4, yc4;
        float* yp = &y4.x; float* yq = &yc4.x;
#pragma unroll
        for (int j = 0; j < 4; ++j) {
            const int cr = ci * 4 + j;
            const float logit = acc[i][j] + bb;
            yp[j] = 10.0f / (1.0f + expf(-logit));
            const float dx = pcs[pr][0] - ccs[cr][0];
            const float dy = pcs[pr][1] - ccs[cr][1];
            const float dz = pcs[pr][2] - ccs[cr][2];
            const float d = sqrtf(dx * dx + dy * dy + dz * dz + 1e-12f);
            yq[j] = fminf(fmaxf(d * 5.0f, 0.0f), 10.0f);
        }
        const size_t o = (size_t)(b * 256 + p0 + pr) * 128 + c0 + ci * 4;
        *reinterpret_cast<float4*>(out + 24576 + o) = y4;
        *reinterpret_cast<float4*>(out + 548864 + o) = yc4;
    }
}

// ---------------------------------------------------------------------------
extern "C" void kernel_launch(void* const* d_in, const int* in_sizes, int n_in,
                              void* d_out, int out_size, void* d_ws, size_t ws_size,
                              hipStream_t stream) {
    const float* prot   = (const float*)d_in[0];
    const float* comp   = (const float*)d_in[1];
    const float* coords = (const float*)d_in[2];
    const float* dism   = (const float*)d_in[3];
    const int*   keep   = (const int*)d_in[4];
    const float* Wp = (const float*)d_in[7];
    const float* bp = (const float*)d_in[8];
    const float* Wc = (const float*)d_in[9];
    const float* bc = (const float*)d_in[10];
    const float* W1 = (const float*)d_in[11];
    const float* b1 = (const float*)d_in[12];
    const float* W2 = (const float*)d_in[13];
    const float* b2 = (const float*)d_in[14];
    float* out = (float*)d_out;
    char* ws = (char*)d_ws;

    k_fusew<<<592, 256, 0, stream>>>(Wp, Wc, bp, bc, W1, b1, W2, coords, dism, out, ws);
    k_gemm<<<576, 512, 0, stream>>>(prot, keep, comp, ws);
    k_pair<<<dim3(2, 8, 16), 256, 0, stream>>>(ws, b2, coords, out);
}